// Round 1
// baseline (463.545 us; speedup 1.0000x reference)
//
#include <hip/hip_runtime.h>

typedef unsigned short u16;
typedef unsigned int   u32;
typedef __attribute__((ext_vector_type(8))) short short8;
typedef __attribute__((ext_vector_type(4))) float f32x4;

// ---------------- ws layout (float element offsets) ----------------
#define OFF_XPS   0            // 10000*128
#define OFF_XPQ   1280000      // 10000*128
#define OFF_SST   2560000      // 10240*32
#define OFF_QST   2887680      // 512*32
#define OFF_PI    2904064      // 512*20*256
#define OFF_PJ    5525504      // 512*20*256
#define OFF_QA    8146944      // 512*256
#define OFF_SGT   8278016      // 256*512  (sum_g transposed [g][b])
#define OFF_F1T   8409088      // 256*512
#define OFF_F2T   8540160      // 512*512
#define OFF_WB    8802304      // ushort region: 3*65536 bf16 weights

__device__ __forceinline__ u16 f2bf(float f){
  union { float f; u32 u; } v; v.f = f;
  u32 u = v.u;
  u32 r = u + 0x7fffu + ((u >> 16) & 1u);
  return (u16)(r >> 16);
}
__device__ __forceinline__ u32 pack2(float a, float b){
  return (u32)f2bf(a) | ((u32)f2bf(b) << 16);
}
__device__ __forceinline__ float sigm(float x){
  return __builtin_amdgcn_rcpf(1.f + __expf(-x));
}

// ---------------- prep: xp tables + bf16 weight conversion ----------------
__global__ __launch_bounds__(256) void prep_kernel(
    const float* __restrict__ emb,
    const float* __restrict__ swih, const float* __restrict__ sbih, const float* __restrict__ sbhh,
    const float* __restrict__ qwih, const float* __restrict__ qbih, const float* __restrict__ qbhh,
    const float* __restrict__ g2w, const float* __restrict__ g3w, const float* __restrict__ g4w,
    float* __restrict__ xps, float* __restrict__ xpq, u16* __restrict__ wb)
{
  const int total = 2560000 + 196608;
  for (int idx = blockIdx.x*256 + threadIdx.x; idx < total; idx += gridDim.x*256){
    if (idx < 2560000){
      const bool isq = idx >= 1280000;
      const int k = isq ? idx - 1280000 : idx;
      const int v = k >> 7, g = k & 127;
      const float* er = emb + v*32;
      const float* wr = (isq ? qwih : swih) + g*32;
      float acc = 0.f;
      #pragma unroll
      for (int q=0;q<8;q++){
        float4 e4 = *(const float4*)(er + q*4);
        float4 w4 = *(const float4*)(wr + q*4);
        acc = fmaf(e4.x, w4.x, acc); acc = fmaf(e4.y, w4.y, acc);
        acc = fmaf(e4.z, w4.z, acc); acc = fmaf(e4.w, w4.w, acc);
      }
      acc += isq ? (qbih[g] + qbhh[g]) : (sbih[g] + sbhh[g]);
      (isq ? xpq : xps)[k] = acc;
    } else {
      const int k = idx - 2560000;
      const float* src = (k < 65536) ? g2w : ((k < 131072) ? g3w : g4w);
      wb[k] = f2bf(src[k & 65535]);
    }
  }
}

// ---------------- LSTM: one wave per sequence (story + question fused) ----------------
__global__ __launch_bounds__(256) void lstm_kernel(
    const int* __restrict__ story, const int* __restrict__ question,
    const float* __restrict__ xps, const float* __restrict__ xpq,
    const float* __restrict__ swhh, const float* __restrict__ qwhh,
    float* __restrict__ sst, float* __restrict__ qst)
{
  __shared__ float hbuf[4][32];
  const int tid = threadIdx.x;
  const int lane = tid & 63;
  const int wv = tid >> 6;
  const int wid = blockIdx.x*4 + wv;
  const bool isq = (wid >= 10240);
  const int seq = isq ? (wid - 10240) : wid;
  const int* toks = isq ? (question + seq*16) : (story + seq*32);
  const int len = isq ? 16 : 32;
  const float* xp  = isq ? xpq : xps;
  const float* whh = isq ? qwhh : swhh;
  float* out = (isq ? qst : sst) + seq*32;

  // register-cache Whh rows 'lane' and 'lane+64'
  float4 w0q[8], w1q[8];
  #pragma unroll
  for (int q=0;q<8;q++){
    w0q[q] = *(const float4*)(whh + lane*32 + q*4);
    w1q[q] = *(const float4*)(whh + (lane+64)*32 + q*4);
  }
  float c = 0.f, h = 0.f;
  if (lane < 32) hbuf[wv][lane] = 0.f;
  __syncthreads();

  for (int t = 0; t < len; ++t){
    const int tok = toks[t];
    const float x0 = xp[tok*128 + lane];
    const float x1 = xp[tok*128 + 64 + lane];
    float a0 = 0.f, a1 = 0.f;
    #pragma unroll
    for (int q=0;q<8;q++){
      float4 h4 = *(const float4*)(&hbuf[wv][q*4]);
      a0 = fmaf(h4.x, w0q[q].x, a0); a0 = fmaf(h4.y, w0q[q].y, a0);
      a0 = fmaf(h4.z, w0q[q].z, a0); a0 = fmaf(h4.w, w0q[q].w, a0);
      a1 = fmaf(h4.x, w1q[q].x, a1); a1 = fmaf(h4.y, w1q[q].y, a1);
      a1 = fmaf(h4.z, w1q[q].z, a1); a1 = fmaf(h4.w, w1q[q].w, a1);
    }
    a0 += x0; a1 += x1;
    const bool lo = (lane < 32);
    // lanes<32: a0=i(sig) a1=g(tanh);  lanes>=32: a0=f(sig) a1=o(sig)
    float s0  = sigm(a0);
    float arg = lo ? (a1 + a1) : a1;
    float s1  = sigm(arg);
    float act1 = lo ? (s1 + s1 - 1.f) : s1;  // tanh(g) or sigmoid(o)
    float p0 = __shfl_xor(s0, 32);
    float p1 = __shfl_xor(act1, 32);
    float iv = lo ? s0   : p0;
    float fv = lo ? p0   : s0;
    float tg = lo ? act1 : p1;
    float ov = lo ? p1   : act1;
    c = fmaf(fv, c, iv*tg);
    float th = sigm(c + c); th = th + th - 1.f;  // tanh(c)
    h = ov * th;
    if (lane < 32) hbuf[wv][lane] = h;
    __syncthreads();
  }
  if (lane < 32) out[lane] = h;
}

// ---------------- pi / pj / qa ----------------
__global__ __launch_bounds__(256) void pipj_kernel(
    const float* __restrict__ sst, const float* __restrict__ qstt,
    const float* __restrict__ g1w, const float* __restrict__ g1b,
    float* __restrict__ pi, float* __restrict__ pj, float* __restrict__ qa)
{
  const int total = 5242880 + 131072;
  for (int idx = blockIdx.x*256 + threadIdx.x; idx < total; idx += gridDim.x*256){
    if (idx < 5242880){
      const bool isj = idx >= 2621440;
      const int k = isj ? idx - 2621440 : idx;
      const int bs = k >> 8, g = k & 255;
      const int s = bs % 20;
      const float* st = sst + bs*32;
      const float* wr = g1w + g*136 + (isj ? 52 : 0);
      float acc = 0.f;
      #pragma unroll
      for (int q=0;q<8;q++){
        float4 s4 = *(const float4*)(st + q*4);
        float4 w4 = *(const float4*)(wr + q*4);
        acc = fmaf(s4.x, w4.x, acc); acc = fmaf(s4.y, w4.y, acc);
        acc = fmaf(s4.z, w4.z, acc); acc = fmaf(s4.w, w4.w, acc);
      }
      acc += wr[32 + s];                     // one-hot tag column
      (isj ? pj : pi)[k] = acc;
    } else {
      const int k = idx - 5242880;
      const int b = k >> 8, g = k & 255;
      const float* qs = qstt + b*32;
      const float* wr = g1w + g*136 + 104;
      float acc = g1b[g];
      #pragma unroll
      for (int q=0;q<8;q++){
        float4 s4 = *(const float4*)(qs + q*4);
        float4 w4 = *(const float4*)(wr + q*4);
        acc = fmaf(s4.x, w4.x, acc); acc = fmaf(s4.y, w4.y, acc);
        acc = fmaf(s4.z, w4.z, acc); acc = fmaf(s4.w, w4.w, acc);
      }
      qa[k] = acc;
    }
  }
}

// ---------------- core relational MLP ----------------
// block = 1 batch element b; 4 waves; 5 tiles of 80 rows; X tile bf16 in LDS [80][264]
// compute Y^T = W * X^T via mfma(A=W rows, B=X rows); D: col=lane&15=m, row=reg=h
#define LDX 264
__global__ __launch_bounds__(256) void relnet_kernel(
    const float* __restrict__ pi, const float* __restrict__ pj, const float* __restrict__ qa,
    const u16* __restrict__ w2, const u16* __restrict__ w3, const u16* __restrict__ w4,
    const float* __restrict__ b2, const float* __restrict__ b3, const float* __restrict__ b4,
    float* __restrict__ sgt)
{
  __shared__ u16 Xs[80*LDX];
  const int tid = threadIdx.x;
  const int lane = tid & 63;
  const int wv  = tid >> 6;       // 0..3 -> h-range wv*64
  const int b   = blockIdx.x;     // 0..511
  const int l15 = lane & 15;
  const int l4  = lane >> 4;      // 0..3

  const float* pib = pi + b*(20*256);
  const float* pjb = pj + b*(20*256);
  const float* qab = qa + b*256;

  float sums[4][4] = {{0.f}};

  for (int t = 0; t < 5; ++t){
    // ---- X1 = relu(pi + pj + qa) -> LDS bf16 ----
    #pragma unroll
    for (int it = 0; it < 10; ++it){
      int u  = it*256 + tid;
      int m  = u >> 5;
      int gq = (u & 31) << 3;
      int R  = t*80 + m;
      int i  = R / 20;
      int j  = R - i*20;
      const float4* pr = (const float4*)(pib + i*256 + gq);
      const float4* qr = (const float4*)(pjb + j*256 + gq);
      const float4* ar = (const float4*)(qab + gq);
      uint4 pk;
      {
        float4 a = pr[0], c4 = qr[0], d4 = ar[0];
        pk.x = pack2(fmaxf(a.x+c4.x+d4.x,0.f), fmaxf(a.y+c4.y+d4.y,0.f));
        pk.y = pack2(fmaxf(a.z+c4.z+d4.z,0.f), fmaxf(a.w+c4.w+d4.w,0.f));
      }
      {
        float4 a = pr[1], c4 = qr[1], d4 = ar[1];
        pk.z = pack2(fmaxf(a.x+c4.x+d4.x,0.f), fmaxf(a.y+c4.y+d4.y,0.f));
        pk.w = pack2(fmaxf(a.z+c4.z+d4.z,0.f), fmaxf(a.w+c4.w+d4.w,0.f));
      }
      *(uint4*)(&Xs[m*LDX + gq]) = pk;
    }
    __syncthreads();

    for (int lay = 0; lay < 3; ++lay){
      const u16*   W    = (lay==0) ? w2 : ((lay==1) ? w3 : w4);
      const float* bias = (lay==0) ? b2 : ((lay==1) ? b3 : b4);
      f32x4 acc[4][5];
      #pragma unroll
      for (int hf=0; hf<4; hf++)
        #pragma unroll
        for (int mf=0; mf<5; mf++)
          acc[hf][mf] = (f32x4){0.f,0.f,0.f,0.f};

      #pragma unroll
      for (int kk = 0; kk < 8; ++kk){
        short8 af[4], xf[5];
        #pragma unroll
        for (int hf=0; hf<4; hf++){
          int row = wv*64 + hf*16 + l15;
          af[hf] = *(const short8*)(W + row*256 + kk*32 + l4*8);
        }
        #pragma unroll
        for (int mf=0; mf<5; mf++){
          xf[mf] = *(const short8*)(&Xs[(mf*16 + l15)*LDX + kk*32 + l4*8]);
        }
        #pragma unroll
        for (int hf=0; hf<4; hf++)
          #pragma unroll
          for (int mf=0; mf<5; mf++)
            acc[hf][mf] = __builtin_amdgcn_mfma_f32_16x16x32_bf16(af[hf], xf[mf], acc[hf][mf], 0, 0, 0);
      }
      __syncthreads();   // all reads of Xs complete

      if (lay < 2){
        // write next X in place: X[m][h..h+3] <- relu(acc + bias)
        #pragma unroll
        for (int hf=0; hf<4; hf++){
          int h0 = wv*64 + hf*16 + l4*4;
          float4 bi = *(const float4*)(bias + h0);
          #pragma unroll
          for (int mf=0; mf<5; mf++){
            int m = mf*16 + l15;
            uint2 pk;
            pk.x = pack2(fmaxf(acc[hf][mf][0]+bi.x,0.f), fmaxf(acc[hf][mf][1]+bi.y,0.f));
            pk.y = pack2(fmaxf(acc[hf][mf][2]+bi.z,0.f), fmaxf(acc[hf][mf][3]+bi.w,0.f));
            *(uint2*)(&Xs[m*LDX + h0]) = pk;
          }
        }
        __syncthreads();
      } else {
        // final layer: accumulate column sums in registers
        #pragma unroll
        for (int hf=0; hf<4; hf++){
          int h0 = wv*64 + hf*16 + l4*4;
          float4 bi = *(const float4*)(bias + h0);
          #pragma unroll
          for (int mf=0; mf<5; mf++){
            sums[hf][0] += fmaxf(acc[hf][mf][0]+bi.x,0.f);
            sums[hf][1] += fmaxf(acc[hf][mf][1]+bi.y,0.f);
            sums[hf][2] += fmaxf(acc[hf][mf][2]+bi.z,0.f);
            sums[hf][3] += fmaxf(acc[hf][mf][3]+bi.w,0.f);
          }
        }
      }
    }
  }

  // reduce over the 16 m-lanes and write sum_gT[g][b]
  #pragma unroll
  for (int hf=0; hf<4; hf++){
    #pragma unroll
    for (int r=0; r<4; r++){
      float v = sums[hf][r];
      v += __shfl_xor(v, 1);
      v += __shfl_xor(v, 2);
      v += __shfl_xor(v, 4);
      v += __shfl_xor(v, 8);
      if (l15 == 0){
        int h = wv*64 + hf*16 + l4*4 + r;
        sgt[h*512 + b] = v;
      }
    }
  }
}

// ---------------- fc layers: in transposed [K][512], w [C][K] ----------------
__global__ __launch_bounds__(256) void fc_kernel(
    const float* __restrict__ inT, const float* __restrict__ w,
    const float* __restrict__ bias, float* __restrict__ out,
    int K, int C, int relu, int transp)
{
  int r  = blockIdx.y*256 + threadIdx.x;  // 0..511
  int c0 = blockIdx.x*2;
  float a0 = 0.f, a1 = 0.f;
  const float* w0 = w + (size_t)c0*K;
  const float* w1 = w0 + K;
  #pragma unroll 4
  for (int k = 0; k < K; ++k){
    float v = inT[k*512 + r];
    a0 = fmaf(w0[k], v, a0);
    a1 = fmaf(w1[k], v, a1);
  }
  a0 += bias[c0]; a1 += bias[c0+1];
  if (relu){ a0 = fmaxf(a0, 0.f); a1 = fmaxf(a1, 0.f); }
  if (transp){
    out[(size_t)c0*512 + r] = a0;
    out[(size_t)(c0+1)*512 + r] = a1;
  } else {
    out[(size_t)r*C + c0] = a0;
    out[(size_t)r*C + c0 + 1] = a1;
  }
}

// ---------------- launch ----------------
extern "C" void kernel_launch(void* const* d_in, const int* in_sizes, int n_in,
                              void* d_out, int out_size, void* d_ws, size_t ws_size,
                              hipStream_t stream)
{
  const int*   story    = (const int*)d_in[0];
  const int*   question = (const int*)d_in[1];
  const float* emb   = (const float*)d_in[2];
  const float* s_wih = (const float*)d_in[3];
  const float* s_whh = (const float*)d_in[4];
  const float* s_bih = (const float*)d_in[5];
  const float* s_bhh = (const float*)d_in[6];
  const float* q_wih = (const float*)d_in[7];
  const float* q_whh = (const float*)d_in[8];
  const float* q_bih = (const float*)d_in[9];
  const float* q_bhh = (const float*)d_in[10];
  const float* g1w = (const float*)d_in[11];
  const float* g1b = (const float*)d_in[12];
  const float* g2w = (const float*)d_in[13];
  const float* g2b = (const float*)d_in[14];
  const float* g3w = (const float*)d_in[15];
  const float* g3b = (const float*)d_in[16];
  const float* g4w = (const float*)d_in[17];
  const float* g4b = (const float*)d_in[18];
  const float* f1w = (const float*)d_in[19];
  const float* f1b = (const float*)d_in[20];
  const float* f2w = (const float*)d_in[21];
  const float* f2b = (const float*)d_in[22];
  const float* f3w = (const float*)d_in[23];
  const float* f3b = (const float*)d_in[24];

  float* ws  = (float*)d_ws;
  float* xps = ws + OFF_XPS;
  float* xpq = ws + OFF_XPQ;
  float* sst = ws + OFF_SST;
  float* qst = ws + OFF_QST;
  float* pi  = ws + OFF_PI;
  float* pj  = ws + OFF_PJ;
  float* qa  = ws + OFF_QA;
  float* sgt = ws + OFF_SGT;
  float* f1t = ws + OFF_F1T;
  float* f2t = ws + OFF_F2T;
  u16*   wb  = (u16*)(ws + OFF_WB);
  u16*   w2b = wb;
  u16*   w3b = wb + 65536;
  u16*   w4b = wb + 131072;

  hipLaunchKernelGGL(prep_kernel, dim3(2048), dim3(256), 0, stream,
                     emb, s_wih, s_bih, s_bhh, q_wih, q_bih, q_bhh,
                     g2w, g3w, g4w, xps, xpq, wb);
  hipLaunchKernelGGL(lstm_kernel, dim3(2688), dim3(256), 0, stream,
                     story, question, xps, xpq, s_whh, q_whh, sst, qst);
  hipLaunchKernelGGL(pipj_kernel, dim3(4096), dim3(256), 0, stream,
                     sst, qst, g1w, g1b, pi, pj, qa);
  hipLaunchKernelGGL(relnet_kernel, dim3(512), dim3(256), 0, stream,
                     pi, pj, qa, w2b, w3b, w4b, g2b, g3b, g4b, sgt);
  hipLaunchKernelGGL(fc_kernel, dim3(128,2), dim3(256), 0, stream,
                     sgt, f1w, f1b, f1t, 256, 256, 1, 1);
  hipLaunchKernelGGL(fc_kernel, dim3(256,2), dim3(256), 0, stream,
                     f1t, f2w, f2b, f2t, 256, 512, 1, 1);
  hipLaunchKernelGGL(fc_kernel, dim3(500,2), dim3(256), 0, stream,
                     f2t, f3w, f3b, (float*)d_out, 512, 1000, 0, 0);
}

// Round 2
// 454.144 us; speedup vs baseline: 1.0207x; 1.0207x over previous
//
#include <hip/hip_runtime.h>

typedef unsigned short u16;
typedef unsigned int   u32;
typedef __attribute__((ext_vector_type(8))) short short8;
typedef __attribute__((ext_vector_type(4))) float f32x4;

// ---------------- ws layout (float element offsets) ----------------
#define OFF_XPS   0            // 10000*128
#define OFF_XPQ   1280000      // 10000*128
#define OFF_QST   2560000      // 512*32
#define OFF_PI    2576384      // 512*20*256
#define OFF_PJ    5197824      // 512*20*256
#define OFF_QA    7819264      // 512*256
#define OFF_SGT   7950336      // 256*512
#define OFF_F1T   8081408      // 256*512
#define OFF_F2T   8212480      // 512*512
#define OFF_TGA   8474624      // 20*256
#define OFF_TGB   8479744      // 20*256
#define OFF_WB    8484864      // u16 region: 3*65536
#define OFF_STB   8583168      // u16 region: 10240*32
#define OFF_WAB   8747008      // u16: 256*32
#define OFF_WBB   8751104      // u16: 256*32
#define OFF_SGP   0            // alias of XPS (dead after lstm): 5*256*512

__device__ __forceinline__ u16 f2bf(float f){
  union { float f; u32 u; } v; v.f = f;
  u32 u = v.u;
  u32 r = u + 0x7fffu + ((u >> 16) & 1u);
  return (u16)(r >> 16);
}
__device__ __forceinline__ u32 pack2(float a, float b){
  u32 r;
  asm("v_cvt_pk_bf16_f32 %0, %1, %2" : "=v"(r) : "v"(a), "v"(b));
  return r;
}
__device__ __forceinline__ float sigm(float x){
  return __builtin_amdgcn_rcpf(1.f + __expf(-x));
}

// ---------------- prep: xp tables + bf16 weights + tag tables ----------------
__global__ __launch_bounds__(256) void prep_kernel(
    const float* __restrict__ emb,
    const float* __restrict__ swih, const float* __restrict__ sbih, const float* __restrict__ sbhh,
    const float* __restrict__ qwih, const float* __restrict__ qbih, const float* __restrict__ qbhh,
    const float* __restrict__ g2w, const float* __restrict__ g3w, const float* __restrict__ g4w,
    const float* __restrict__ g1w,
    float* __restrict__ xps, float* __restrict__ xpq, u16* __restrict__ wb,
    u16* __restrict__ wab, u16* __restrict__ wbb,
    float* __restrict__ tga, float* __restrict__ tgb)
{
  const int total = 2560000 + 196608 + 16384 + 10240;
  for (int idx = blockIdx.x*256 + threadIdx.x; idx < total; idx += gridDim.x*256){
    if (idx < 2560000){
      const bool isq = idx >= 1280000;
      const int k = isq ? idx - 1280000 : idx;
      const int v = k >> 7, g = k & 127;
      const float* er = emb + v*32;
      const float* wr = (isq ? qwih : swih) + g*32;
      float acc = 0.f;
      #pragma unroll
      for (int q=0;q<8;q++){
        float4 e4 = *(const float4*)(er + q*4);
        float4 w4 = *(const float4*)(wr + q*4);
        acc = fmaf(e4.x, w4.x, acc); acc = fmaf(e4.y, w4.y, acc);
        acc = fmaf(e4.z, w4.z, acc); acc = fmaf(e4.w, w4.w, acc);
      }
      acc += isq ? (qbih[g] + qbhh[g]) : (sbih[g] + sbhh[g]);
      (isq ? xpq : xps)[k] = acc;
    } else if (idx < 2756608){
      const int k = idx - 2560000;
      const float* src = (k < 65536) ? g2w : ((k < 131072) ? g3w : g4w);
      wb[k] = f2bf(src[k & 65535]);
    } else if (idx < 2772992){
      const int k = idx - 2756608;
      if (k < 8192) wab[k] = f2bf(g1w[(k>>5)*136 + (k&31)]);
      else { const int k2 = k - 8192; wbb[k2] = f2bf(g1w[(k2>>5)*136 + 52 + (k2&31)]); }
    } else {
      const int k = idx - 2772992;
      if (k < 5120){ const int s = k >> 8, g = k & 255; tga[k] = g1w[g*136 + 32 + s]; }
      else { const int k2 = k - 5120; const int s = k2 >> 8, g = k2 & 255; tgb[k2] = g1w[g*136 + 84 + s]; }
    }
  }
}

// ---------------- LSTM: 1 wave per sequence, x prefetched to regs ----------------
template<int LEN>
__device__ __forceinline__ float lstm_run(
    const int* __restrict__ toks, const float* __restrict__ xp,
    const float4* w0q, const float4* w1q, float* hbuf, int lane)
{
  float x0[LEN], x1[LEN];
  #pragma unroll
  for (int t=0;t<LEN;t++){
    const int tok = toks[t];
    x0[t] = xp[tok*128 + lane];
    x1[t] = xp[tok*128 + 64 + lane];
  }
  float c = 0.f, h = 0.f;
  if (lane < 32) hbuf[lane] = 0.f;
  __syncthreads();
  const bool lo = (lane < 32);
  #pragma unroll
  for (int t=0;t<LEN;t++){
    float a0 = 0.f, a1 = 0.f;
    #pragma unroll
    for (int q=0;q<8;q++){
      float4 h4 = *(const float4*)(&hbuf[q*4]);
      a0 = fmaf(h4.x, w0q[q].x, a0); a0 = fmaf(h4.y, w0q[q].y, a0);
      a0 = fmaf(h4.z, w0q[q].z, a0); a0 = fmaf(h4.w, w0q[q].w, a0);
      a1 = fmaf(h4.x, w1q[q].x, a1); a1 = fmaf(h4.y, w1q[q].y, a1);
      a1 = fmaf(h4.z, w1q[q].z, a1); a1 = fmaf(h4.w, w1q[q].w, a1);
    }
    a0 += x0[t]; a1 += x1[t];
    float s0  = sigm(a0);
    float arg = lo ? (a1 + a1) : a1;
    float s1  = sigm(arg);
    float act1 = lo ? (s1 + s1 - 1.f) : s1;
    float p0 = __shfl_xor(s0, 32);
    float p1 = __shfl_xor(act1, 32);
    float iv = lo ? s0   : p0;
    float fv = lo ? p0   : s0;
    float tg = lo ? act1 : p1;
    float ov = lo ? p1   : act1;
    c = fmaf(fv, c, iv*tg);
    float th = sigm(c + c); th = th + th - 1.f;
    h = ov * th;
    __syncthreads();
    if (lane < 32) hbuf[lane] = h;
    __syncthreads();
  }
  return h;
}

__global__ __launch_bounds__(64) void lstm_kernel(
    const int* __restrict__ story, const int* __restrict__ question,
    const float* __restrict__ xps, const float* __restrict__ xpq,
    const float* __restrict__ swhh, const float* __restrict__ qwhh,
    u16* __restrict__ stb, float* __restrict__ qst)
{
  __shared__ float hbuf[32];
  const int lane = threadIdx.x;
  const int wid = blockIdx.x;
  const bool isq = (wid >= 10240);
  const int seq = isq ? (wid - 10240) : wid;
  const float* whh = isq ? qwhh : swhh;

  float4 w0q[8], w1q[8];
  #pragma unroll
  for (int q=0;q<8;q++){
    w0q[q] = *(const float4*)(whh + lane*32 + q*4);
    w1q[q] = *(const float4*)(whh + (lane+64)*32 + q*4);
  }
  if (isq){
    float h = lstm_run<16>(question + seq*16, xpq, w0q, w1q, hbuf, lane);
    if (lane < 32) qst[seq*32 + lane] = h;
  } else {
    float h = lstm_run<32>(story + seq*32, xps, w0q, w1q, hbuf, lane);
    if (lane < 32) stb[seq*32 + lane] = f2bf(h);
  }
}

// ---------------- qa = q_state @ Wq^T + g1_b ----------------
__global__ __launch_bounds__(256) void qa_kernel(
    const float* __restrict__ qst, const float* __restrict__ g1w,
    const float* __restrict__ g1b, float* __restrict__ qa)
{
  const int idx = blockIdx.x*256 + threadIdx.x;   // 131072
  const int b = idx >> 8, g = idx & 255;
  const float* qs = qst + b*32;
  const float* wr = g1w + g*136 + 104;
  float acc = g1b[g];
  #pragma unroll
  for (int q=0;q<8;q++){
    float4 s4 = *(const float4*)(qs + q*4);
    float4 w4 = *(const float4*)(wr + q*4);
    acc = fmaf(s4.x, w4.x, acc); acc = fmaf(s4.y, w4.y, acc);
    acc = fmaf(s4.z, w4.z, acc); acc = fmaf(s4.w, w4.w, acc);
  }
  qa[idx] = acc;
}

// ---------------- pi / pj via MFMA (K=32, one step) ----------------
// block: 64 bs rows x 256 g; 4 waves, wave owns g range wv*64
__global__ __launch_bounds__(256) void pipj_kernel(
    const u16* __restrict__ stb, const u16* __restrict__ wab, const u16* __restrict__ wbb,
    const float* __restrict__ tga, const float* __restrict__ tgb,
    float* __restrict__ pi, float* __restrict__ pj)
{
  const int tid = threadIdx.x;
  const int lane = tid & 63;
  const int wv = tid >> 6;
  const int l15 = lane & 15;
  const int l4 = lane >> 4;
  const int bs0 = blockIdx.x * 64;
  const bool isj = blockIdx.y;
  const u16* wB = isj ? wbb : wab;
  const float* tg = isj ? tgb : tga;
  float* out = isj ? pj : pi;

  short8 af[4], bf[4];
  #pragma unroll
  for (int mf=0; mf<4; mf++)
    af[mf] = *(const short8*)(stb + (bs0 + mf*16 + l15)*32 + l4*8);
  #pragma unroll
  for (int nf=0; nf<4; nf++)
    bf[nf] = *(const short8*)(wB + (wv*64 + nf*16 + l15)*32 + l4*8);

  #pragma unroll
  for (int mf=0; mf<4; mf++){
    #pragma unroll
    for (int nf=0; nf<4; nf++){
      f32x4 acc = (f32x4){0.f,0.f,0.f,0.f};
      acc = __builtin_amdgcn_mfma_f32_16x16x32_bf16(af[mf], bf[nf], acc, 0, 0, 0);
      const int g = wv*64 + nf*16 + l15;
      #pragma unroll
      for (int r=0; r<4; r++){
        const int bs = bs0 + mf*16 + l4*4 + r;
        const int s = bs % 20;
        out[bs*256 + g] = acc[r] + tg[s*256 + g];
      }
    }
  }
}

// ---------------- core relational MLP: 1 tile per block ----------------
// grid (512 b, 5 t); 8 waves; X tile bf16 in LDS [80][256] XOR-swizzled
#define SWZ(m, col) ((m)*256 + ((col) ^ (((m)&7)<<3)))
__global__ __launch_bounds__(512, 6) void relnet_kernel(
    const float* __restrict__ pi, const float* __restrict__ pj, const float* __restrict__ qa,
    const u16* __restrict__ w2, const u16* __restrict__ w3, const u16* __restrict__ w4,
    const float* __restrict__ b2, const float* __restrict__ b3, const float* __restrict__ b4,
    float* __restrict__ sgp)
{
  __shared__ u16 Xs[80*256];
  const int tid = threadIdx.x;
  const int lane = tid & 63;
  const int wv  = tid >> 6;       // 0..7 -> h-range wv*32
  const int b   = blockIdx.x;
  const int t   = blockIdx.y;
  const int l15 = lane & 15;
  const int l4  = lane >> 4;

  const float* pib = pi + b*(20*256);
  const float* pjb = pj + b*(20*256);
  const float* qab = qa + b*256;

  float sums[2][4] = {{0.f}};

  // ---- X1 = relu(pi + pj + qa) -> LDS bf16 (swizzled) ----
  #pragma unroll
  for (int it = 0; it < 5; ++it){
    int u  = it*512 + tid;
    int m  = u >> 5;
    int gq = (u & 31) << 3;
    int R  = t*80 + m;
    int i  = R / 20;
    int j  = R - i*20;
    const float4* pr = (const float4*)(pib + i*256 + gq);
    const float4* qr = (const float4*)(pjb + j*256 + gq);
    const float4* ar = (const float4*)(qab + gq);
    uint4 pk;
    {
      float4 a = pr[0], c4 = qr[0], d4 = ar[0];
      pk.x = pack2(fmaxf(a.x+c4.x+d4.x,0.f), fmaxf(a.y+c4.y+d4.y,0.f));
      pk.y = pack2(fmaxf(a.z+c4.z+d4.z,0.f), fmaxf(a.w+c4.w+d4.w,0.f));
    }
    {
      float4 a = pr[1], c4 = qr[1], d4 = ar[1];
      pk.z = pack2(fmaxf(a.x+c4.x+d4.x,0.f), fmaxf(a.y+c4.y+d4.y,0.f));
      pk.w = pack2(fmaxf(a.z+c4.z+d4.z,0.f), fmaxf(a.w+c4.w+d4.w,0.f));
    }
    *(uint4*)(&Xs[SWZ(m, gq)]) = pk;
  }
  __syncthreads();

  for (int lay = 0; lay < 3; ++lay){
    const u16*   W    = (lay==0) ? w2 : ((lay==1) ? w3 : w4);
    const float* bias = (lay==0) ? b2 : ((lay==1) ? b3 : b4);
    f32x4 acc[2][5];
    #pragma unroll
    for (int hf=0; hf<2; hf++)
      #pragma unroll
      for (int mf=0; mf<5; mf++)
        acc[hf][mf] = (f32x4){0.f,0.f,0.f,0.f};

    #pragma unroll
    for (int kk = 0; kk < 8; ++kk){
      short8 af[2], xf[5];
      #pragma unroll
      for (int hf=0; hf<2; hf++){
        int row = wv*32 + hf*16 + l15;
        af[hf] = *(const short8*)(W + row*256 + kk*32 + l4*8);
      }
      #pragma unroll
      for (int mf=0; mf<5; mf++){
        xf[mf] = *(const short8*)(&Xs[SWZ(mf*16 + l15, kk*32 + l4*8)]);
      }
      #pragma unroll
      for (int hf=0; hf<2; hf++)
        #pragma unroll
        for (int mf=0; mf<5; mf++)
          acc[hf][mf] = __builtin_amdgcn_mfma_f32_16x16x32_bf16(af[hf], xf[mf], acc[hf][mf], 0, 0, 0);
    }

    if (lay < 2){
      __syncthreads();   // all reads of Xs complete
      #pragma unroll
      for (int hf=0; hf<2; hf++){
        int h0 = wv*32 + hf*16 + l4*4;
        float4 bi = *(const float4*)(bias + h0);
        #pragma unroll
        for (int mf=0; mf<5; mf++){
          int m = mf*16 + l15;
          uint2 pk;
          pk.x = pack2(fmaxf(acc[hf][mf][0]+bi.x,0.f), fmaxf(acc[hf][mf][1]+bi.y,0.f));
          pk.y = pack2(fmaxf(acc[hf][mf][2]+bi.z,0.f), fmaxf(acc[hf][mf][3]+bi.w,0.f));
          *(uint2*)(&Xs[SWZ(m, h0)]) = pk;
        }
      }
      __syncthreads();
    } else {
      #pragma unroll
      for (int hf=0; hf<2; hf++){
        int h0 = wv*32 + hf*16 + l4*4;
        float4 bi = *(const float4*)(bias + h0);
        #pragma unroll
        for (int mf=0; mf<5; mf++){
          sums[hf][0] += fmaxf(acc[hf][mf][0]+bi.x,0.f);
          sums[hf][1] += fmaxf(acc[hf][mf][1]+bi.y,0.f);
          sums[hf][2] += fmaxf(acc[hf][mf][2]+bi.z,0.f);
          sums[hf][3] += fmaxf(acc[hf][mf][3]+bi.w,0.f);
        }
      }
    }
  }

  // reduce over the 16 m-lanes, write partial sum sgp[t][h][b]
  #pragma unroll
  for (int hf=0; hf<2; hf++){
    #pragma unroll
    for (int r=0; r<4; r++){
      float v = sums[hf][r];
      v += __shfl_xor(v, 1);
      v += __shfl_xor(v, 2);
      v += __shfl_xor(v, 4);
      v += __shfl_xor(v, 8);
      if (l15 == 0){
        int h = wv*32 + hf*16 + l4*4 + r;
        sgp[t*131072 + h*512 + b] = v;
      }
    }
  }
}

// ---------------- partial-sum reduce: sgt = sum_t sgp[t] ----------------
__global__ __launch_bounds__(256) void sgred_kernel(
    const float* __restrict__ sgp, float* __restrict__ sgt)
{
  const int idx = blockIdx.x*256 + threadIdx.x;  // 131072
  float v = 0.f;
  #pragma unroll
  for (int t=0;t<5;t++) v += sgp[t*131072 + idx];
  sgt[idx] = v;
}

// ---------------- fc layers: in transposed [K][512], w [C][K] ----------------
template<int NC>
__global__ __launch_bounds__(256) void fc_kernel(
    const float* __restrict__ inT, const float* __restrict__ w,
    const float* __restrict__ bias, float* __restrict__ out,
    int K, int C, int relu, int transp)
{
  int r  = blockIdx.y*256 + threadIdx.x;  // 0..511
  int c0 = blockIdx.x*NC;
  float a[NC];
  #pragma unroll
  for (int c=0;c<NC;c++) a[c] = 0.f;
  #pragma unroll 2
  for (int k = 0; k < K; ++k){
    float v = inT[k*512 + r];
    #pragma unroll
    for (int c=0;c<NC;c++) a[c] = fmaf(w[(size_t)(c0+c)*K + k], v, a[c]);
  }
  #pragma unroll
  for (int c=0;c<NC;c++){
    float x = a[c] + bias[c0+c];
    if (relu) x = fmaxf(x, 0.f);
    if (transp) out[(size_t)(c0+c)*512 + r] = x;
    else        out[(size_t)r*C + c0 + c] = x;
  }
}

// ---------------- launch ----------------
extern "C" void kernel_launch(void* const* d_in, const int* in_sizes, int n_in,
                              void* d_out, int out_size, void* d_ws, size_t ws_size,
                              hipStream_t stream)
{
  const int*   story    = (const int*)d_in[0];
  const int*   question = (const int*)d_in[1];
  const float* emb   = (const float*)d_in[2];
  const float* s_wih = (const float*)d_in[3];
  const float* s_whh = (const float*)d_in[4];
  const float* s_bih = (const float*)d_in[5];
  const float* s_bhh = (const float*)d_in[6];
  const float* q_wih = (const float*)d_in[7];
  const float* q_whh = (const float*)d_in[8];
  const float* q_bih = (const float*)d_in[9];
  const float* q_bhh = (const float*)d_in[10];
  const float* g1w = (const float*)d_in[11];
  const float* g1b = (const float*)d_in[12];
  const float* g2w = (const float*)d_in[13];
  const float* g2b = (const float*)d_in[14];
  const float* g3w = (const float*)d_in[15];
  const float* g3b = (const float*)d_in[16];
  const float* g4w = (const float*)d_in[17];
  const float* g4b = (const float*)d_in[18];
  const float* f1w = (const float*)d_in[19];
  const float* f1b = (const float*)d_in[20];
  const float* f2w = (const float*)d_in[21];
  const float* f2b = (const float*)d_in[22];
  const float* f3w = (const float*)d_in[23];
  const float* f3b = (const float*)d_in[24];

  float* ws  = (float*)d_ws;
  float* xps = ws + OFF_XPS;
  float* xpq = ws + OFF_XPQ;
  float* qst = ws + OFF_QST;
  float* pi  = ws + OFF_PI;
  float* pj  = ws + OFF_PJ;
  float* qa  = ws + OFF_QA;
  float* sgt = ws + OFF_SGT;
  float* f1t = ws + OFF_F1T;
  float* f2t = ws + OFF_F2T;
  float* tga = ws + OFF_TGA;
  float* tgb = ws + OFF_TGB;
  float* sgp = ws + OFF_SGP;
  u16*   wb  = (u16*)(ws + OFF_WB);
  u16*   w2b = wb;
  u16*   w3b = wb + 65536;
  u16*   w4b = wb + 131072;
  u16*   stb = (u16*)(ws + OFF_STB);
  u16*   wab = (u16*)(ws + OFF_WAB);
  u16*   wbb = (u16*)(ws + OFF_WBB);

  prep_kernel<<<dim3(4096), dim3(256), 0, stream>>>(
      emb, s_wih, s_bih, s_bhh, q_wih, q_bih, q_bhh,
      g2w, g3w, g4w, g1w, xps, xpq, wb, wab, wbb, tga, tgb);
  lstm_kernel<<<dim3(10752), dim3(64), 0, stream>>>(
      story, question, xps, xpq, s_whh, q_whh, stb, qst);
  qa_kernel<<<dim3(512), dim3(256), 0, stream>>>(qst, g1w, g1b, qa);
  pipj_kernel<<<dim3(160,2), dim3(256), 0, stream>>>(
      stb, wab, wbb, tga, tgb, pi, pj);
  relnet_kernel<<<dim3(512,5), dim3(512), 0, stream>>>(
      pi, pj, qa, w2b, w3b, w4b, g2b, g3b, g4b, sgp);
  sgred_kernel<<<dim3(512), dim3(256), 0, stream>>>(sgp, sgt);
  fc_kernel<4><<<dim3(64,2), dim3(256), 0, stream>>>(sgt, f1w, f1b, f1t, 256, 256, 1, 1);
  fc_kernel<4><<<dim3(128,2), dim3(256), 0, stream>>>(f1t, f2w, f2b, f2t, 256, 512, 1, 1);
  fc_kernel<8><<<dim3(125,2), dim3(256), 0, stream>>>(f2t, f3w, f3b, (float*)d_out, 512, 1000, 0, 0);
}

// Round 3
// 333.605 us; speedup vs baseline: 1.3895x; 1.3613x over previous
//
#include <hip/hip_runtime.h>

typedef unsigned short u16;
typedef unsigned int   u32;
typedef __attribute__((ext_vector_type(8))) short short8;
typedef __attribute__((ext_vector_type(4))) float f32x4;

// ---------------- ws layout (float element offsets) ----------------
#define OFF_XPS   0            // 10000*128 (gate-permuted xp story)
#define OFF_XPQ   1280000      // 10000*128 (gate-permuted xp question)
#define OFF_QST   2560000      // 512*32
#define OFF_PI    2576384      // 512*20*256
#define OFF_PJ    5197824      // 512*20*256
#define OFF_QA    7819264      // 512*256
#define OFF_TGA   7950336      // 20*256
#define OFF_TGB   7955456      // 20*256
#define OFF_WB    7960576      // u16 x 196608 (g2/g3/g4 bf16)
#define OFF_STB   8058880      // u16 x 327680 (story h bf16)
#define OFF_WAB   8222720      // u16 x 8192
#define OFF_WBB   8226816      // u16 x 8192
#define OFF_WHHS  8230912      // u16 x 4096
#define OFF_WHHQ  8232960      // u16 x 4096
#define OFF_WF1   8235008      // u16 x 65536
#define OFF_WF2   8267776      // u16 x 131072
#define OFF_WF3   8333312      // u16 x 524288 (1024x512, zero-padded)
// aliased into XPS/XPQ region (dead after lstm):
#define OFF_SGP   0            // 5*256*512 fl
#define OFF_SGB   655360       // u16 x 131072 (sum_g bf16 [b][256])
#define OFF_ACT1  720896       // u16 x 131072 ([b][256])
#define OFF_ACT2  786432       // u16 x 262144 ([b][512])

__device__ __forceinline__ u16 f2bf(float f){
  union { float f; u32 u; } v; v.f = f;
  u32 u = v.u;
  u32 r = u + 0x7fffu + ((u >> 16) & 1u);
  return (u16)(r >> 16);
}
__device__ __forceinline__ u32 pack2(float a, float b){
  u32 r;
  asm("v_cvt_pk_bf16_f32 %0, %1, %2" : "=v"(r) : "v"(a), "v"(b));
  return r;
}
__device__ __forceinline__ float sigm(float x){
  return __builtin_amdgcn_rcpf(1.f + __expf(-x));
}

// ---------------- prep: tables + bf16 weight conversion ----------------
__global__ __launch_bounds__(256) void prep_kernel(
    const float* __restrict__ emb,
    const float* __restrict__ swih, const float* __restrict__ sbih, const float* __restrict__ sbhh,
    const float* __restrict__ qwih, const float* __restrict__ qbih, const float* __restrict__ qbhh,
    const float* __restrict__ g2w, const float* __restrict__ g3w, const float* __restrict__ g4w,
    const float* __restrict__ g1w,
    const float* __restrict__ swhh, const float* __restrict__ qwhh,
    const float* __restrict__ f1w, const float* __restrict__ f2w, const float* __restrict__ f3w,
    float* __restrict__ xps, float* __restrict__ xpq, u16* __restrict__ wb,
    u16* __restrict__ wab, u16* __restrict__ wbb,
    float* __restrict__ tga, float* __restrict__ tgb,
    u16* __restrict__ whhbs, u16* __restrict__ whhbq,
    u16* __restrict__ wf1, u16* __restrict__ wf2, u16* __restrict__ wf3)
{
  const int A = 2560000;
  const int B = A + 196608;
  const int C = B + 16384;
  const int D = C + 10240;
  const int E = D + 8192;
  const int F = E + 65536;
  const int G = F + 131072;
  const int H = G + 524288;
  for (int idx = blockIdx.x*256 + threadIdx.x; idx < H; idx += gridDim.x*256){
    if (idx < A){
      const bool isq = idx >= 1280000;
      const int k = isq ? idx - 1280000 : idx;
      const int v = k >> 7, g = k & 127;
      const float* er = emb + v*32;
      const float* wr = (isq ? qwih : swih) + g*32;
      float acc = 0.f;
      #pragma unroll
      for (int q=0;q<8;q++){
        float4 e4 = *(const float4*)(er + q*4);
        float4 w4 = *(const float4*)(wr + q*4);
        acc = fmaf(e4.x, w4.x, acc); acc = fmaf(e4.y, w4.y, acc);
        acc = fmaf(e4.z, w4.z, acc); acc = fmaf(e4.w, w4.w, acc);
      }
      acc += isq ? (qbih[g] + qbhh[g]) : (sbih[g] + sbhh[g]);
      // gate-permuted store: slot = (g&15)*8 + (g>>4)
      const int sidx = v*128 + (g&15)*8 + (g>>4);
      (isq ? xpq : xps)[sidx] = acc;
    } else if (idx < B){
      const int k = idx - A;
      const float* src = (k < 65536) ? g2w : ((k < 131072) ? g3w : g4w);
      wb[k] = f2bf(src[k & 65535]);
    } else if (idx < C){
      const int k = idx - B;
      if (k < 8192) wab[k] = f2bf(g1w[(k>>5)*136 + (k&31)]);
      else { const int k2 = k - 8192; wbb[k2] = f2bf(g1w[(k2>>5)*136 + 52 + (k2&31)]); }
    } else if (idx < D){
      const int k = idx - C;
      if (k < 5120){ const int s = k >> 8, g = k & 255; tga[k] = g1w[g*136 + 32 + s]; }
      else { const int k2 = k - 5120; const int s = k2 >> 8, g = k2 & 255; tgb[k2] = g1w[g*136 + 84 + s]; }
    } else if (idx < E){
      const int k = idx - D;
      if (k < 4096) whhbs[k] = f2bf(swhh[k]);
      else whhbq[k-4096] = f2bf(qwhh[k-4096]);
    } else if (idx < F){
      const int k = idx - E;
      wf1[k] = f2bf(f1w[k]);
    } else if (idx < G){
      const int k = idx - F;
      wf2[k] = f2bf(f2w[k]);
    } else {
      const int k = idx - G;
      const int o = k >> 9, kk = k & 511;
      wf3[k] = (o < 1000) ? f2bf(f3w[o*512 + kk]) : (u16)0;
    }
  }
}

// ---------------- LSTM via MFMA: 16 sequences per wave ----------------
// gates[s][g] = sum_k h[s][k]*Whh[g][k] + xp[tok_s][g]
// A-frag = h rows (seq=l15, k=l4*8+j); B-frag = Whh rows (gate=f*16+l15).
// D: col(l15)=gate, row(l4*4+r)=seq. Frag roles: i={0,1} f={2,3} g={4,5} o={6,7}.
template<int LEN>
__device__ __forceinline__ void lstm_mfma_run(
    const int* __restrict__ toks, int s0,
    const float* __restrict__ xpr, const u16* __restrict__ whhb,
    u16* __restrict__ hl, int lane, float* h0r, float* h1r)
{
  const int l15 = lane & 15, l4 = lane >> 4;
  short8 wf[8];
  #pragma unroll
  for (int f=0; f<8; f++)
    wf[f] = *(const short8*)(whhb + (f*16+l15)*32 + l4*8);
  short8 ha = (short8){0,0,0,0,0,0,0,0};
  float c0[4] = {0,0,0,0}, c1[4] = {0,0,0,0};
  int tk[4];
  #pragma unroll
  for (int r=0;r<4;r++) tk[r] = toks[(s0 + l4*4 + r)*LEN];
  float4 xa[4], xb[4];
  #pragma unroll
  for (int r=0;r<4;r++){
    xa[r] = *(const float4*)(xpr + tk[r]*128 + l15*8);
    xb[r] = *(const float4*)(xpr + tk[r]*128 + l15*8 + 4);
  }
  #pragma unroll
  for (int t=0; t<LEN; ++t){
    int tkn[4];
    if (t+1 < LEN){
      #pragma unroll
      for (int r=0;r<4;r++) tkn[r] = toks[(s0 + l4*4 + r)*LEN + t + 1];
    }
    const f32x4 z = (f32x4){0.f,0.f,0.f,0.f};
    f32x4 acc[8];
    #pragma unroll
    for (int f=0; f<8; f++)
      acc[f] = __builtin_amdgcn_mfma_f32_16x16x32_bf16(ha, wf[f], z, 0, 0, 0);
    float4 na[4], nb[4];
    if (t+1 < LEN){
      #pragma unroll
      for (int r=0;r<4;r++){
        na[r] = *(const float4*)(xpr + tkn[r]*128 + l15*8);
        nb[r] = *(const float4*)(xpr + tkn[r]*128 + l15*8 + 4);
      }
    }
    #pragma unroll
    for (int r=0;r<4;r++){
      float i0 = sigm(acc[0][r] + xa[r].x);
      float f0 = sigm(acc[2][r] + xa[r].z);
      float g0 = 2.f*sigm(2.f*(acc[4][r] + xb[r].x)) - 1.f;
      float o0 = sigm(acc[6][r] + xb[r].z);
      c0[r] = fmaf(f0, c0[r], i0*g0);
      h0r[r] = o0 * (2.f*sigm(2.f*c0[r]) - 1.f);
      float i1 = sigm(acc[1][r] + xa[r].y);
      float f1v = sigm(acc[3][r] + xa[r].w);
      float g1v = 2.f*sigm(2.f*(acc[5][r] + xb[r].y)) - 1.f;
      float o1 = sigm(acc[7][r] + xb[r].w);
      c1[r] = fmaf(f1v, c1[r], i1*g1v);
      h1r[r] = o1 * (2.f*sigm(2.f*c1[r]) - 1.f);
    }
    if (t+1 < LEN){
      #pragma unroll
      for (int r=0;r<4;r++){
        hl[(l4*4+r)*32 + l15]      = f2bf(h0r[r]);
        hl[(l4*4+r)*32 + 16 + l15] = f2bf(h1r[r]);
      }
      __syncthreads();
      ha = *(const short8*)(hl + l15*32 + l4*8);
      #pragma unroll
      for (int r=0;r<4;r++){ xa[r] = na[r]; xb[r] = nb[r]; }
    }
  }
}

__global__ __launch_bounds__(64) void lstm_kernel(
    const int* __restrict__ story, const int* __restrict__ question,
    const float* __restrict__ xprs, const float* __restrict__ xprq,
    const u16* __restrict__ whhbs, const u16* __restrict__ whhbq,
    u16* __restrict__ stb, float* __restrict__ qst)
{
  __shared__ u16 hl[512];
  const int lane = threadIdx.x;
  const int w = blockIdx.x;
  const int l15 = lane & 15, l4 = lane >> 4;
  float h0r[4], h1r[4];
  if (w >= 640){
    const int s0 = (w - 640)*16;
    lstm_mfma_run<16>(question, s0, xprq, whhbq, hl, lane, h0r, h1r);
    #pragma unroll
    for (int r=0;r<4;r++){
      qst[(s0 + l4*4 + r)*32 + l15]      = h0r[r];
      qst[(s0 + l4*4 + r)*32 + 16 + l15] = h1r[r];
    }
  } else {
    const int s0 = w*16;
    lstm_mfma_run<32>(story, s0, xprs, whhbs, hl, lane, h0r, h1r);
    #pragma unroll
    for (int r=0;r<4;r++){
      stb[(s0 + l4*4 + r)*32 + l15]      = f2bf(h0r[r]);
      stb[(s0 + l4*4 + r)*32 + 16 + l15] = f2bf(h1r[r]);
    }
  }
}

// ---------------- qa = q_state @ Wq^T + g1_b ----------------
__global__ __launch_bounds__(256) void qa_kernel(
    const float* __restrict__ qst, const float* __restrict__ g1w,
    const float* __restrict__ g1b, float* __restrict__ qa)
{
  const int idx = blockIdx.x*256 + threadIdx.x;   // 131072
  const int b = idx >> 8, g = idx & 255;
  const float* qs = qst + b*32;
  const float* wr = g1w + g*136 + 104;
  float acc = g1b[g];
  #pragma unroll
  for (int q=0;q<8;q++){
    float4 s4 = *(const float4*)(qs + q*4);
    float4 w4 = *(const float4*)(wr + q*4);
    acc = fmaf(s4.x, w4.x, acc); acc = fmaf(s4.y, w4.y, acc);
    acc = fmaf(s4.z, w4.z, acc); acc = fmaf(s4.w, w4.w, acc);
  }
  qa[idx] = acc;
}

// ---------------- pi / pj via MFMA (K=32, one step) ----------------
__global__ __launch_bounds__(256) void pipj_kernel(
    const u16* __restrict__ stb, const u16* __restrict__ wab, const u16* __restrict__ wbb,
    const float* __restrict__ tga, const float* __restrict__ tgb,
    float* __restrict__ pi, float* __restrict__ pj)
{
  const int tid = threadIdx.x;
  const int lane = tid & 63;
  const int wv = tid >> 6;
  const int l15 = lane & 15;
  const int l4 = lane >> 4;
  const int bs0 = blockIdx.x * 64;
  const bool isj = blockIdx.y;
  const u16* wB = isj ? wbb : wab;
  const float* tg = isj ? tgb : tga;
  float* out = isj ? pj : pi;

  short8 af[4], bf[4];
  #pragma unroll
  for (int mf=0; mf<4; mf++)
    af[mf] = *(const short8*)(stb + (bs0 + mf*16 + l15)*32 + l4*8);
  #pragma unroll
  for (int nf=0; nf<4; nf++)
    bf[nf] = *(const short8*)(wB + (wv*64 + nf*16 + l15)*32 + l4*8);

  #pragma unroll
  for (int mf=0; mf<4; mf++){
    #pragma unroll
    for (int nf=0; nf<4; nf++){
      f32x4 acc = (f32x4){0.f,0.f,0.f,0.f};
      acc = __builtin_amdgcn_mfma_f32_16x16x32_bf16(af[mf], bf[nf], acc, 0, 0, 0);
      const int g = wv*64 + nf*16 + l15;
      #pragma unroll
      for (int r=0; r<4; r++){
        const int bs = bs0 + mf*16 + l4*4 + r;
        const int s = bs % 20;
        out[bs*256 + g] = acc[r] + tg[s*256 + g];
      }
    }
  }
}

// ---------------- core relational MLP: 1 tile per block, 4 waves ----------------
// grid (512 b, 5 t); X tile bf16 in LDS [80][256] XOR-swizzled
#define SWZ(m, col) ((m)*256 + ((col) ^ (((m)&7)<<3)))
__global__ __launch_bounds__(256, 3) void relnet_kernel(
    const float* __restrict__ pi, const float* __restrict__ pj, const float* __restrict__ qa,
    const u16* __restrict__ w2, const u16* __restrict__ w3, const u16* __restrict__ w4,
    const float* __restrict__ b2, const float* __restrict__ b3, const float* __restrict__ b4,
    float* __restrict__ sgp)
{
  __shared__ u16 Xs[80*256];
  const int tid = threadIdx.x;
  const int lane = tid & 63;
  const int wv  = tid >> 6;       // 0..3 -> h-range wv*64
  const int b   = blockIdx.x;
  const int t   = blockIdx.y;
  const int l15 = lane & 15;
  const int l4  = lane >> 4;

  const float* pib = pi + b*(20*256);
  const float* pjb = pj + b*(20*256);
  const float* qab = qa + b*256;

  float sums[4][4] = {{0.f}};

  // ---- X1 = relu(pi + pj + qa) -> LDS bf16 (swizzled) ----
  #pragma unroll
  for (int it = 0; it < 10; ++it){
    int u  = it*256 + tid;
    int m  = u >> 5;
    int gq = (u & 31) << 3;
    int R  = t*80 + m;
    int i  = R / 20;
    int j  = R - i*20;
    const float4* pr = (const float4*)(pib + i*256 + gq);
    const float4* qr = (const float4*)(pjb + j*256 + gq);
    const float4* ar = (const float4*)(qab + gq);
    uint4 pk;
    {
      float4 a = pr[0], c4 = qr[0], d4 = ar[0];
      pk.x = pack2(fmaxf(a.x+c4.x+d4.x,0.f), fmaxf(a.y+c4.y+d4.y,0.f));
      pk.y = pack2(fmaxf(a.z+c4.z+d4.z,0.f), fmaxf(a.w+c4.w+d4.w,0.f));
    }
    {
      float4 a = pr[1], c4 = qr[1], d4 = ar[1];
      pk.z = pack2(fmaxf(a.x+c4.x+d4.x,0.f), fmaxf(a.y+c4.y+d4.y,0.f));
      pk.w = pack2(fmaxf(a.z+c4.z+d4.z,0.f), fmaxf(a.w+c4.w+d4.w,0.f));
    }
    *(uint4*)(&Xs[SWZ(m, gq)]) = pk;
  }
  __syncthreads();

  for (int lay = 0; lay < 3; ++lay){
    const u16*   W    = (lay==0) ? w2 : ((lay==1) ? w3 : w4);
    const float* bias = (lay==0) ? b2 : ((lay==1) ? b3 : b4);
    f32x4 acc[4][5];
    #pragma unroll
    for (int hf=0; hf<4; hf++)
      #pragma unroll
      for (int mf=0; mf<5; mf++)
        acc[hf][mf] = (f32x4){0.f,0.f,0.f,0.f};

    #pragma unroll
    for (int kk = 0; kk < 8; ++kk){
      short8 af[4], xf[5];
      #pragma unroll
      for (int hf=0; hf<4; hf++){
        int row = wv*64 + hf*16 + l15;
        af[hf] = *(const short8*)(W + row*256 + kk*32 + l4*8);
      }
      #pragma unroll
      for (int mf=0; mf<5; mf++){
        xf[mf] = *(const short8*)(&Xs[SWZ(mf*16 + l15, kk*32 + l4*8)]);
      }
      #pragma unroll
      for (int hf=0; hf<4; hf++)
        #pragma unroll
        for (int mf=0; mf<5; mf++)
          acc[hf][mf] = __builtin_amdgcn_mfma_f32_16x16x32_bf16(af[hf], xf[mf], acc[hf][mf], 0, 0, 0);
    }

    if (lay < 2){
      __syncthreads();   // all reads of Xs complete
      #pragma unroll
      for (int hf=0; hf<4; hf++){
        int h0 = wv*64 + hf*16 + l4*4;
        float4 bi = *(const float4*)(bias + h0);
        #pragma unroll
        for (int mf=0; mf<5; mf++){
          int m = mf*16 + l15;
          uint2 pk;
          pk.x = pack2(fmaxf(acc[hf][mf][0]+bi.x,0.f), fmaxf(acc[hf][mf][1]+bi.y,0.f));
          pk.y = pack2(fmaxf(acc[hf][mf][2]+bi.z,0.f), fmaxf(acc[hf][mf][3]+bi.w,0.f));
          *(uint2*)(&Xs[SWZ(m, h0)]) = pk;
        }
      }
      __syncthreads();
    } else {
      #pragma unroll
      for (int hf=0; hf<4; hf++){
        int h0 = wv*64 + hf*16 + l4*4;
        float4 bi = *(const float4*)(bias + h0);
        #pragma unroll
        for (int mf=0; mf<5; mf++){
          sums[hf][0] += fmaxf(acc[hf][mf][0]+bi.x,0.f);
          sums[hf][1] += fmaxf(acc[hf][mf][1]+bi.y,0.f);
          sums[hf][2] += fmaxf(acc[hf][mf][2]+bi.z,0.f);
          sums[hf][3] += fmaxf(acc[hf][mf][3]+bi.w,0.f);
        }
      }
    }
  }

  // reduce over the 16 m-lanes, write partial sum sgp[t][h][b]
  #pragma unroll
  for (int hf=0; hf<4; hf++){
    #pragma unroll
    for (int r=0; r<4; r++){
      float v = sums[hf][r];
      v += __shfl_xor(v, 1);
      v += __shfl_xor(v, 2);
      v += __shfl_xor(v, 4);
      v += __shfl_xor(v, 8);
      if (l15 == 0){
        int h = wv*64 + hf*16 + l4*4 + r;
        sgp[t*131072 + h*512 + b] = v;
      }
    }
  }
}

// ---------------- partial-sum reduce -> bf16 [b][256] ----------------
__global__ __launch_bounds__(256) void sgred_kernel(
    const float* __restrict__ sgp, u16* __restrict__ sgb)
{
  const int idx = blockIdx.x*256 + threadIdx.x;  // g*512 + b
  float v = 0.f;
  #pragma unroll
  for (int t=0;t<5;t++) v += sgp[t*131072 + idx];
  const int g = idx >> 9, b = idx & 511;
  sgb[b*256 + g] = f2bf(v);
}

// ---------------- fc layers via MFMA ----------------
// in: bf16 [512][K] rows; w: bf16 [O][K]; out: bf16 [b][O] or f32 [b][OREAL]
template<int HF, int KK, int OREAL, int MODE>
__global__ __launch_bounds__(256) void fcm_kernel(
    const u16* __restrict__ in, const u16* __restrict__ w,
    const float* __restrict__ bias, void* __restrict__ outp)
{
  const int K = KK*32;
  const int O = HF*64;
  const int tid = threadIdx.x, lane = tid & 63, wv = tid >> 6;
  const int l15 = lane & 15, l4 = lane >> 4;
  const int b0 = blockIdx.x*16;
  f32x4 acc[HF];
  #pragma unroll
  for (int hf=0; hf<HF; hf++) acc[hf] = (f32x4){0.f,0.f,0.f,0.f};
  #pragma unroll 4
  for (int kk=0; kk<KK; ++kk){
    short8 xf = *(const short8*)(in + (b0+l15)*K + kk*32 + l4*8);
    #pragma unroll
    for (int hf=0; hf<HF; hf++){
      short8 af = *(const short8*)(w + (wv*HF*16 + hf*16 + l15)*K + kk*32 + l4*8);
      acc[hf] = __builtin_amdgcn_mfma_f32_16x16x32_bf16(af, xf, acc[hf], 0, 0, 0);
    }
  }
  const int b = b0 + l15;
  #pragma unroll
  for (int hf=0; hf<HF; hf++){
    const int o0 = wv*HF*16 + hf*16 + l4*4;
    float v[4];
    #pragma unroll
    for (int r=0;r<4;r++){
      float bv = (o0+r < OREAL) ? bias[o0+r] : 0.f;
      v[r] = acc[hf][r] + bv;
    }
    if (MODE == 0){
      uint2 pk;
      pk.x = pack2(fmaxf(v[0],0.f), fmaxf(v[1],0.f));
      pk.y = pack2(fmaxf(v[2],0.f), fmaxf(v[3],0.f));
      *(uint2*)((u16*)outp + (size_t)b*O + o0) = pk;
    } else {
      float* of = (float*)outp;
      #pragma unroll
      for (int r=0;r<4;r++)
        if (o0+r < OREAL) of[(size_t)b*OREAL + o0 + r] = v[r];
    }
  }
}

// ---------------- launch ----------------
extern "C" void kernel_launch(void* const* d_in, const int* in_sizes, int n_in,
                              void* d_out, int out_size, void* d_ws, size_t ws_size,
                              hipStream_t stream)
{
  const int*   story    = (const int*)d_in[0];
  const int*   question = (const int*)d_in[1];
  const float* emb   = (const float*)d_in[2];
  const float* s_wih = (const float*)d_in[3];
  const float* s_whh = (const float*)d_in[4];
  const float* s_bih = (const float*)d_in[5];
  const float* s_bhh = (const float*)d_in[6];
  const float* q_wih = (const float*)d_in[7];
  const float* q_whh = (const float*)d_in[8];
  const float* q_bih = (const float*)d_in[9];
  const float* q_bhh = (const float*)d_in[10];
  const float* g1w = (const float*)d_in[11];
  const float* g1b = (const float*)d_in[12];
  const float* g2w = (const float*)d_in[13];
  const float* g2b = (const float*)d_in[14];
  const float* g3w = (const float*)d_in[15];
  const float* g3b = (const float*)d_in[16];
  const float* g4w = (const float*)d_in[17];
  const float* g4b = (const float*)d_in[18];
  const float* f1w = (const float*)d_in[19];
  const float* f1b = (const float*)d_in[20];
  const float* f2w = (const float*)d_in[21];
  const float* f2b = (const float*)d_in[22];
  const float* f3w = (const float*)d_in[23];
  const float* f3b = (const float*)d_in[24];

  float* ws  = (float*)d_ws;
  float* xps = ws + OFF_XPS;
  float* xpq = ws + OFF_XPQ;
  float* qst = ws + OFF_QST;
  float* pi  = ws + OFF_PI;
  float* pj  = ws + OFF_PJ;
  float* qa  = ws + OFF_QA;
  float* tga = ws + OFF_TGA;
  float* tgb = ws + OFF_TGB;
  float* sgp = ws + OFF_SGP;
  u16*   wb    = (u16*)(ws + OFF_WB);
  u16*   w2b   = wb;
  u16*   w3b   = wb + 65536;
  u16*   w4b   = wb + 131072;
  u16*   stb   = (u16*)(ws + OFF_STB);
  u16*   wab   = (u16*)(ws + OFF_WAB);
  u16*   wbb   = (u16*)(ws + OFF_WBB);
  u16*   whhbs = (u16*)(ws + OFF_WHHS);
  u16*   whhbq = (u16*)(ws + OFF_WHHQ);
  u16*   wf1   = (u16*)(ws + OFF_WF1);
  u16*   wf2   = (u16*)(ws + OFF_WF2);
  u16*   wf3   = (u16*)(ws + OFF_WF3);
  u16*   sgb   = (u16*)(ws + OFF_SGB);
  u16*   act1  = (u16*)(ws + OFF_ACT1);
  u16*   act2  = (u16*)(ws + OFF_ACT2);

  prep_kernel<<<dim3(4096), dim3(256), 0, stream>>>(
      emb, s_wih, s_bih, s_bhh, q_wih, q_bih, q_bhh,
      g2w, g3w, g4w, g1w, s_whh, q_whh, f1w, f2w, f3w,
      xps, xpq, wb, wab, wbb, tga, tgb, whhbs, whhbq, wf1, wf2, wf3);
  lstm_kernel<<<dim3(672), dim3(64), 0, stream>>>(
      story, question, xps, xpq, whhbs, whhbq, stb, qst);
  qa_kernel<<<dim3(512), dim3(256), 0, stream>>>(qst, g1w, g1b, qa);
  pipj_kernel<<<dim3(160,2), dim3(256), 0, stream>>>(
      stb, wab, wbb, tga, tgb, pi, pj);
  relnet_kernel<<<dim3(512,5), dim3(256), 0, stream>>>(
      pi, pj, qa, w2b, w3b, w4b, g2b, g3b, g4b, sgp);
  sgred_kernel<<<dim3(512), dim3(256), 0, stream>>>(sgp, sgb);
  fcm_kernel<4,8,256,0><<<dim3(32), dim3(256), 0, stream>>>(sgb, wf1, f1b, act1);
  fcm_kernel<8,8,512,0><<<dim3(32), dim3(256), 0, stream>>>(act1, wf2, f2b, act2);
  fcm_kernel<16,16,1000,1><<<dim3(32), dim3(256), 0, stream>>>(act2, wf3, f3b, (float*)d_out);
}

// Round 4
// 308.985 us; speedup vs baseline: 1.5002x; 1.0797x over previous
//
#include <hip/hip_runtime.h>

typedef unsigned short u16;
typedef unsigned int   u32;
typedef __attribute__((ext_vector_type(8))) short short8;
typedef __attribute__((ext_vector_type(4))) float f32x4;

// ---------------- ws layout (float element offsets) ----------------
#define OFF_XPS   0            // 10000*128 (gate-permuted xp story)
#define OFF_XPQ   1280000      // 10000*128 (gate-permuted xp question)
#define OFF_QST   2560000      // 512*32
#define OFF_PI    2576384      // 512*20*256
#define OFF_PJ    5197824      // 512*20*256
#define OFF_QA    7819264      // 512*256
#define OFF_TGA   7950336      // 20*256
#define OFF_TGB   7955456      // 20*256
#define OFF_WB    7960576      // u16 x 196608 (g2/g3/g4 bf16)
#define OFF_STB   8058880      // u16 x 327680 (story h bf16)
#define OFF_WAB   8222720      // u16 x 8192
#define OFF_WBB   8226816      // u16 x 8192
#define OFF_WHHS  8230912      // u16 x 4096
#define OFF_WHHQ  8232960      // u16 x 4096
#define OFF_WF1   8235008      // u16 x 65536
#define OFF_WF2   8267776      // u16 x 131072
#define OFF_WF3   8333312      // u16 x 524288 (1024x512, zero-padded)
// aliased into XPS/XPQ region (dead after lstm):
#define OFF_SGP   0            // 5*256*512 fl
#define OFF_SGB   655360       // u16 x 131072 (sum_g bf16 [b][256])
#define OFF_ACT1  720896       // u16 x 131072 ([b][256])
#define OFF_ACT2  786432       // u16 x 262144 ([b][512])

__device__ __forceinline__ u16 f2bf(float f){
  union { float f; u32 u; } v; v.f = f;
  u32 u = v.u;
  u32 r = u + 0x7fffu + ((u >> 16) & 1u);
  return (u16)(r >> 16);
}
__device__ __forceinline__ u32 pack2(float a, float b){
  u32 r;
  asm("v_cvt_pk_bf16_f32 %0, %1, %2" : "=v"(r) : "v"(a), "v"(b));
  return r;
}
__device__ __forceinline__ float sigm(float x){
  return __builtin_amdgcn_rcpf(1.f + __expf(-x));
}

// ---------------- prep: tables + bf16 weight conversion ----------------
__global__ __launch_bounds__(256) void prep_kernel(
    const float* __restrict__ emb,
    const float* __restrict__ swih, const float* __restrict__ sbih, const float* __restrict__ sbhh,
    const float* __restrict__ qwih, const float* __restrict__ qbih, const float* __restrict__ qbhh,
    const float* __restrict__ g2w, const float* __restrict__ g3w, const float* __restrict__ g4w,
    const float* __restrict__ g1w,
    const float* __restrict__ swhh, const float* __restrict__ qwhh,
    const float* __restrict__ f1w, const float* __restrict__ f2w, const float* __restrict__ f3w,
    float* __restrict__ xps, float* __restrict__ xpq, u16* __restrict__ wb,
    u16* __restrict__ wab, u16* __restrict__ wbb,
    float* __restrict__ tga, float* __restrict__ tgb,
    u16* __restrict__ whhbs, u16* __restrict__ whhbq,
    u16* __restrict__ wf1, u16* __restrict__ wf2, u16* __restrict__ wf3)
{
  const int A = 2560000;
  const int B = A + 196608;
  const int C = B + 16384;
  const int D = C + 10240;
  const int E = D + 8192;
  const int F = E + 65536;
  const int G = F + 131072;
  const int H = G + 524288;
  for (int idx = blockIdx.x*256 + threadIdx.x; idx < H; idx += gridDim.x*256){
    if (idx < A){
      const bool isq = idx >= 1280000;
      const int k = isq ? idx - 1280000 : idx;
      const int v = k >> 7, g = k & 127;
      const float* er = emb + v*32;
      const float* wr = (isq ? qwih : swih) + g*32;
      float acc = 0.f;
      #pragma unroll
      for (int q=0;q<8;q++){
        float4 e4 = *(const float4*)(er + q*4);
        float4 w4 = *(const float4*)(wr + q*4);
        acc = fmaf(e4.x, w4.x, acc); acc = fmaf(e4.y, w4.y, acc);
        acc = fmaf(e4.z, w4.z, acc); acc = fmaf(e4.w, w4.w, acc);
      }
      acc += isq ? (qbih[g] + qbhh[g]) : (sbih[g] + sbhh[g]);
      // gate-permuted store: slot = (g&15)*8 + (g>>4)
      const int sidx = v*128 + (g&15)*8 + (g>>4);
      (isq ? xpq : xps)[sidx] = acc;
    } else if (idx < B){
      const int k = idx - A;
      const float* src = (k < 65536) ? g2w : ((k < 131072) ? g3w : g4w);
      wb[k] = f2bf(src[k & 65535]);
    } else if (idx < C){
      const int k = idx - B;
      if (k < 8192) wab[k] = f2bf(g1w[(k>>5)*136 + (k&31)]);
      else { const int k2 = k - 8192; wbb[k2] = f2bf(g1w[(k2>>5)*136 + 52 + (k2&31)]); }
    } else if (idx < D){
      const int k = idx - C;
      if (k < 5120){ const int s = k >> 8, g = k & 255; tga[k] = g1w[g*136 + 32 + s]; }
      else { const int k2 = k - 5120; const int s = k2 >> 8, g = k2 & 255; tgb[k2] = g1w[g*136 + 84 + s]; }
    } else if (idx < E){
      const int k = idx - D;
      if (k < 4096) whhbs[k] = f2bf(swhh[k]);
      else whhbq[k-4096] = f2bf(qwhh[k-4096]);
    } else if (idx < F){
      const int k = idx - E;
      wf1[k] = f2bf(f1w[k]);
    } else if (idx < G){
      const int k = idx - F;
      wf2[k] = f2bf(f2w[k]);
    } else {
      const int k = idx - G;
      const int o = k >> 9, kk = k & 511;
      wf3[k] = (o < 1000) ? f2bf(f3w[o*512 + kk]) : (u16)0;
    }
  }
}

// ---------------- LSTM via MFMA: 16 sequences per wave ----------------
// gates[s][g] = sum_k h[s][k]*Whh[g][k] + xp[tok_s][g]
// A-frag = h rows (seq=l15, k=l4*8+j); B-frag = Whh rows (gate=f*16+l15).
// D: col(l15)=gate, row(l4*4+r)=seq. Frag roles: i={0,1} f={2,3} g={4,5} o={6,7}.
template<int LEN>
__device__ __forceinline__ void lstm_mfma_run(
    const int* __restrict__ toks, int s0,
    const float* __restrict__ xpr, const u16* __restrict__ whhb,
    u16* __restrict__ hl, int lane, float* h0r, float* h1r)
{
  const int l15 = lane & 15, l4 = lane >> 4;
  short8 wf[8];
  #pragma unroll
  for (int f=0; f<8; f++)
    wf[f] = *(const short8*)(whhb + (f*16+l15)*32 + l4*8);
  short8 ha = (short8){0,0,0,0,0,0,0,0};
  float c0[4] = {0,0,0,0}, c1[4] = {0,0,0,0};
  int tk[4];
  #pragma unroll
  for (int r=0;r<4;r++) tk[r] = toks[(s0 + l4*4 + r)*LEN];
  float4 xa[4], xb[4];
  #pragma unroll
  for (int r=0;r<4;r++){
    xa[r] = *(const float4*)(xpr + tk[r]*128 + l15*8);
    xb[r] = *(const float4*)(xpr + tk[r]*128 + l15*8 + 4);
  }
  #pragma unroll
  for (int t=0; t<LEN; ++t){
    int tkn[4];
    if (t+1 < LEN){
      #pragma unroll
      for (int r=0;r<4;r++) tkn[r] = toks[(s0 + l4*4 + r)*LEN + t + 1];
    }
    const f32x4 z = (f32x4){0.f,0.f,0.f,0.f};
    f32x4 acc[8];
    #pragma unroll
    for (int f=0; f<8; f++)
      acc[f] = __builtin_amdgcn_mfma_f32_16x16x32_bf16(ha, wf[f], z, 0, 0, 0);
    float4 na[4], nb[4];
    if (t+1 < LEN){
      #pragma unroll
      for (int r=0;r<4;r++){
        na[r] = *(const float4*)(xpr + tkn[r]*128 + l15*8);
        nb[r] = *(const float4*)(xpr + tkn[r]*128 + l15*8 + 4);
      }
    }
    #pragma unroll
    for (int r=0;r<4;r++){
      float i0 = sigm(acc[0][r] + xa[r].x);
      float f0 = sigm(acc[2][r] + xa[r].z);
      float g0 = 2.f*sigm(2.f*(acc[4][r] + xb[r].x)) - 1.f;
      float o0 = sigm(acc[6][r] + xb[r].z);
      c0[r] = fmaf(f0, c0[r], i0*g0);
      h0r[r] = o0 * (2.f*sigm(2.f*c0[r]) - 1.f);
      float i1 = sigm(acc[1][r] + xa[r].y);
      float f1v = sigm(acc[3][r] + xa[r].w);
      float g1v = 2.f*sigm(2.f*(acc[5][r] + xb[r].y)) - 1.f;
      float o1 = sigm(acc[7][r] + xb[r].w);
      c1[r] = fmaf(f1v, c1[r], i1*g1v);
      h1r[r] = o1 * (2.f*sigm(2.f*c1[r]) - 1.f);
    }
    if (t+1 < LEN){
      #pragma unroll
      for (int r=0;r<4;r++){
        hl[(l4*4+r)*32 + l15]      = f2bf(h0r[r]);
        hl[(l4*4+r)*32 + 16 + l15] = f2bf(h1r[r]);
      }
      __syncthreads();
      ha = *(const short8*)(hl + l15*32 + l4*8);
      #pragma unroll
      for (int r=0;r<4;r++){ xa[r] = na[r]; xb[r] = nb[r]; }
    }
  }
}

__global__ __launch_bounds__(64) void lstm_kernel(
    const int* __restrict__ story, const int* __restrict__ question,
    const float* __restrict__ xprs, const float* __restrict__ xprq,
    const u16* __restrict__ whhbs, const u16* __restrict__ whhbq,
    u16* __restrict__ stb, float* __restrict__ qst)
{
  __shared__ u16 hl[512];
  const int lane = threadIdx.x;
  const int w = blockIdx.x;
  const int l15 = lane & 15, l4 = lane >> 4;
  float h0r[4], h1r[4];
  if (w >= 640){
    const int s0 = (w - 640)*16;
    lstm_mfma_run<16>(question, s0, xprq, whhbq, hl, lane, h0r, h1r);
    #pragma unroll
    for (int r=0;r<4;r++){
      qst[(s0 + l4*4 + r)*32 + l15]      = h0r[r];
      qst[(s0 + l4*4 + r)*32 + 16 + l15] = h1r[r];
    }
  } else {
    const int s0 = w*16;
    lstm_mfma_run<32>(story, s0, xprs, whhbs, hl, lane, h0r, h1r);
    #pragma unroll
    for (int r=0;r<4;r++){
      stb[(s0 + l4*4 + r)*32 + l15]      = f2bf(h0r[r]);
      stb[(s0 + l4*4 + r)*32 + 16 + l15] = f2bf(h1r[r]);
    }
  }
}

// ---------------- pi / pj via MFMA (K=32, one step); y==2 computes qa ----------------
__global__ __launch_bounds__(256) void pipj_kernel(
    const u16* __restrict__ stb, const u16* __restrict__ wab, const u16* __restrict__ wbb,
    const float* __restrict__ tga, const float* __restrict__ tgb,
    const float* __restrict__ qst, const float* __restrict__ g1w, const float* __restrict__ g1b,
    float* __restrict__ pi, float* __restrict__ pj, float* __restrict__ qa)
{
  const int tid = threadIdx.x;
  if (blockIdx.y == 2){
    // qa = q_state @ Wq^T + g1_b
    for (int idx = blockIdx.x*256 + tid; idx < 131072; idx += 160*256){
      const int b = idx >> 8, g = idx & 255;
      const float* qs = qst + b*32;
      const float* wr = g1w + g*136 + 104;
      float acc = g1b[g];
      #pragma unroll
      for (int q=0;q<8;q++){
        float4 s4 = *(const float4*)(qs + q*4);
        float4 w4 = *(const float4*)(wr + q*4);
        acc = fmaf(s4.x, w4.x, acc); acc = fmaf(s4.y, w4.y, acc);
        acc = fmaf(s4.z, w4.z, acc); acc = fmaf(s4.w, w4.w, acc);
      }
      qa[idx] = acc;
    }
    return;
  }
  const int lane = tid & 63;
  const int wv = tid >> 6;
  const int l15 = lane & 15;
  const int l4 = lane >> 4;
  const int bs0 = blockIdx.x * 64;
  const bool isj = blockIdx.y;
  const u16* wB = isj ? wbb : wab;
  const float* tg = isj ? tgb : tga;
  float* out = isj ? pj : pi;

  short8 af[4], bf[4];
  #pragma unroll
  for (int mf=0; mf<4; mf++)
    af[mf] = *(const short8*)(stb + (bs0 + mf*16 + l15)*32 + l4*8);
  #pragma unroll
  for (int nf=0; nf<4; nf++)
    bf[nf] = *(const short8*)(wB + (wv*64 + nf*16 + l15)*32 + l4*8);

  #pragma unroll
  for (int mf=0; mf<4; mf++){
    #pragma unroll
    for (int nf=0; nf<4; nf++){
      f32x4 acc = (f32x4){0.f,0.f,0.f,0.f};
      acc = __builtin_amdgcn_mfma_f32_16x16x32_bf16(af[mf], bf[nf], acc, 0, 0, 0);
      const int g = wv*64 + nf*16 + l15;
      #pragma unroll
      for (int r=0; r<4; r++){
        const int bs = bs0 + mf*16 + l4*4 + r;
        const int s = bs % 20;
        out[bs*256 + g] = acc[r] + tg[s*256 + g];
      }
    }
  }
}

// ---------------- core relational MLP: 1 tile per block, 4 waves ----------------
// grid (512 b, 5 t); X tile bf16 in LDS [80][256] XOR-swizzled
#define SWZ(m, col) ((m)*256 + ((col) ^ (((m)&7)<<3)))
__global__ __launch_bounds__(256) void relnet_kernel(
    const float* __restrict__ pi, const float* __restrict__ pj, const float* __restrict__ qa,
    const u16* __restrict__ w2, const u16* __restrict__ w3, const u16* __restrict__ w4,
    const float* __restrict__ b2, const float* __restrict__ b3, const float* __restrict__ b4,
    float* __restrict__ sgp)
{
  __shared__ u16 Xs[80*256];
  const int tid = threadIdx.x;
  const int lane = tid & 63;
  const int wv  = tid >> 6;       // 0..3 -> h-range wv*64
  const int b   = blockIdx.x;
  const int t   = blockIdx.y;
  const int l15 = lane & 15;
  const int l4  = lane >> 4;

  const float* pib = pi + b*(20*256);
  const float* pjb = pj + b*(20*256);
  const float* qab = qa + b*256;

  float sums[4][4] = {{0.f}};

  // ---- X1 = relu(pi + pj + qa) -> LDS bf16 (swizzled) ----
  #pragma unroll
  for (int it = 0; it < 10; ++it){
    int u  = it*256 + tid;
    int m  = u >> 5;
    int gq = (u & 31) << 3;
    int R  = t*80 + m;
    int i  = R / 20;
    int j  = R - i*20;
    const float4* pr = (const float4*)(pib + i*256 + gq);
    const float4* qr = (const float4*)(pjb + j*256 + gq);
    const float4* ar = (const float4*)(qab + gq);
    uint4 pk;
    {
      float4 a = pr[0], c4 = qr[0], d4 = ar[0];
      pk.x = pack2(fmaxf(a.x+c4.x+d4.x,0.f), fmaxf(a.y+c4.y+d4.y,0.f));
      pk.y = pack2(fmaxf(a.z+c4.z+d4.z,0.f), fmaxf(a.w+c4.w+d4.w,0.f));
    }
    {
      float4 a = pr[1], c4 = qr[1], d4 = ar[1];
      pk.z = pack2(fmaxf(a.x+c4.x+d4.x,0.f), fmaxf(a.y+c4.y+d4.y,0.f));
      pk.w = pack2(fmaxf(a.z+c4.z+d4.z,0.f), fmaxf(a.w+c4.w+d4.w,0.f));
    }
    *(uint4*)(&Xs[SWZ(m, gq)]) = pk;
  }
  __syncthreads();

  for (int lay = 0; lay < 3; ++lay){
    const u16*   W    = (lay==0) ? w2 : ((lay==1) ? w3 : w4);
    const float* bias = (lay==0) ? b2 : ((lay==1) ? b3 : b4);
    f32x4 acc[4][5];
    #pragma unroll
    for (int hf=0; hf<4; hf++)
      #pragma unroll
      for (int mf=0; mf<5; mf++)
        acc[hf][mf] = (f32x4){0.f,0.f,0.f,0.f};

    #pragma unroll
    for (int kk = 0; kk < 8; ++kk){
      short8 af[4], xf[5];
      #pragma unroll
      for (int hf=0; hf<4; hf++){
        int row = wv*64 + hf*16 + l15;
        af[hf] = *(const short8*)(W + row*256 + kk*32 + l4*8);
      }
      #pragma unroll
      for (int mf=0; mf<5; mf++){
        xf[mf] = *(const short8*)(&Xs[SWZ(mf*16 + l15, kk*32 + l4*8)]);
      }
      #pragma unroll
      for (int hf=0; hf<4; hf++)
        #pragma unroll
        for (int mf=0; mf<5; mf++)
          acc[hf][mf] = __builtin_amdgcn_mfma_f32_16x16x32_bf16(af[hf], xf[mf], acc[hf][mf], 0, 0, 0);
    }

    if (lay < 2){
      __syncthreads();   // all reads of Xs complete
      #pragma unroll
      for (int hf=0; hf<4; hf++){
        int h0 = wv*64 + hf*16 + l4*4;
        float4 bi = *(const float4*)(bias + h0);
        #pragma unroll
        for (int mf=0; mf<5; mf++){
          int m = mf*16 + l15;
          uint2 pk;
          pk.x = pack2(fmaxf(acc[hf][mf][0]+bi.x,0.f), fmaxf(acc[hf][mf][1]+bi.y,0.f));
          pk.y = pack2(fmaxf(acc[hf][mf][2]+bi.z,0.f), fmaxf(acc[hf][mf][3]+bi.w,0.f));
          *(uint2*)(&Xs[SWZ(m, h0)]) = pk;
        }
      }
      __syncthreads();
    } else {
      #pragma unroll
      for (int hf=0; hf<4; hf++){
        int h0 = wv*64 + hf*16 + l4*4;
        float4 bi = *(const float4*)(bias + h0);
        #pragma unroll
        for (int mf=0; mf<5; mf++){
          sums[hf][0] += fmaxf(acc[hf][mf][0]+bi.x,0.f);
          sums[hf][1] += fmaxf(acc[hf][mf][1]+bi.y,0.f);
          sums[hf][2] += fmaxf(acc[hf][mf][2]+bi.z,0.f);
          sums[hf][3] += fmaxf(acc[hf][mf][3]+bi.w,0.f);
        }
      }
    }
  }

  // reduce over the 16 m-lanes, write partial sum sgp[t][h][b]
  #pragma unroll
  for (int hf=0; hf<4; hf++){
    #pragma unroll
    for (int r=0; r<4; r++){
      float v = sums[hf][r];
      v += __shfl_xor(v, 1);
      v += __shfl_xor(v, 2);
      v += __shfl_xor(v, 4);
      v += __shfl_xor(v, 8);
      if (l15 == 0){
        int h = wv*64 + hf*16 + l4*4 + r;
        sgp[t*131072 + h*512 + b] = v;
      }
    }
  }
}

// ---------------- partial-sum reduce -> bf16 [b][256] ----------------
__global__ __launch_bounds__(256) void sgred_kernel(
    const float* __restrict__ sgp, u16* __restrict__ sgb)
{
  const int idx = blockIdx.x*256 + threadIdx.x;  // g*512 + b
  float v = 0.f;
  #pragma unroll
  for (int t=0;t<5;t++) v += sgp[t*131072 + idx];
  const int g = idx >> 9, b = idx & 511;
  sgb[b*256 + g] = f2bf(v);
}

// ---------------- fc layers via MFMA ----------------
// in: bf16 [512][K] rows; w: bf16 [O][K]; out: bf16 [b][O] or f32 [b][OREAL]
template<int HF, int KK, int OREAL, int MODE>
__global__ __launch_bounds__(256) void fcm_kernel(
    const u16* __restrict__ in, const u16* __restrict__ w,
    const float* __restrict__ bias, void* __restrict__ outp)
{
  const int K = KK*32;
  const int O = HF*64;
  const int tid = threadIdx.x, lane = tid & 63, wv = tid >> 6;
  const int l15 = lane & 15, l4 = lane >> 4;
  const int b0 = blockIdx.x*16;
  f32x4 acc[HF];
  #pragma unroll
  for (int hf=0; hf<HF; hf++) acc[hf] = (f32x4){0.f,0.f,0.f,0.f};
  #pragma unroll 4
  for (int kk=0; kk<KK; ++kk){
    short8 xf = *(const short8*)(in + (b0+l15)*K + kk*32 + l4*8);
    #pragma unroll
    for (int hf=0; hf<HF; hf++){
      short8 af = *(const short8*)(w + (wv*HF*16 + hf*16 + l15)*K + kk*32 + l4*8);
      acc[hf] = __builtin_amdgcn_mfma_f32_16x16x32_bf16(af, xf, acc[hf], 0, 0, 0);
    }
  }
  const int b = b0 + l15;
  #pragma unroll
  for (int hf=0; hf<HF; hf++){
    const int o0 = wv*HF*16 + hf*16 + l4*4;
    float v[4];
    #pragma unroll
    for (int r=0;r<4;r++){
      float bv = (o0+r < OREAL) ? bias[o0+r] : 0.f;
      v[r] = acc[hf][r] + bv;
    }
    if (MODE == 0){
      uint2 pk;
      pk.x = pack2(fmaxf(v[0],0.f), fmaxf(v[1],0.f));
      pk.y = pack2(fmaxf(v[2],0.f), fmaxf(v[3],0.f));
      *(uint2*)((u16*)outp + (size_t)b*O + o0) = pk;
    } else {
      float* of = (float*)outp;
      #pragma unroll
      for (int r=0;r<4;r++)
        if (o0+r < OREAL) of[(size_t)b*OREAL + o0 + r] = v[r];
    }
  }
}

// ---------------- launch ----------------
extern "C" void kernel_launch(void* const* d_in, const int* in_sizes, int n_in,
                              void* d_out, int out_size, void* d_ws, size_t ws_size,
                              hipStream_t stream)
{
  const int*   story    = (const int*)d_in[0];
  const int*   question = (const int*)d_in[1];
  const float* emb   = (const float*)d_in[2];
  const float* s_wih = (const float*)d_in[3];
  const float* s_whh = (const float*)d_in[4];
  const float* s_bih = (const float*)d_in[5];
  const float* s_bhh = (const float*)d_in[6];
  const float* q_wih = (const float*)d_in[7];
  const float* q_whh = (const float*)d_in[8];
  const float* q_bih = (const float*)d_in[9];
  const float* q_bhh = (const float*)d_in[10];
  const float* g1w = (const float*)d_in[11];
  const float* g1b = (const float*)d_in[12];
  const float* g2w = (const float*)d_in[13];
  const float* g2b = (const float*)d_in[14];
  const float* g3w = (const float*)d_in[15];
  const float* g3b = (const float*)d_in[16];
  const float* g4w = (const float*)d_in[17];
  const float* g4b = (const float*)d_in[18];
  const float* f1w = (const float*)d_in[19];
  const float* f1b = (const float*)d_in[20];
  const float* f2w = (const float*)d_in[21];
  const float* f2b = (const float*)d_in[22];
  const float* f3w = (const float*)d_in[23];
  const float* f3b = (const float*)d_in[24];

  float* ws  = (float*)d_ws;
  float* xps = ws + OFF_XPS;
  float* xpq = ws + OFF_XPQ;
  float* qst = ws + OFF_QST;
  float* pi  = ws + OFF_PI;
  float* pj  = ws + OFF_PJ;
  float* qa  = ws + OFF_QA;
  float* tga = ws + OFF_TGA;
  float* tgb = ws + OFF_TGB;
  float* sgp = ws + OFF_SGP;
  u16*   wb    = (u16*)(ws + OFF_WB);
  u16*   w2b   = wb;
  u16*   w3b   = wb + 65536;
  u16*   w4b   = wb + 131072;
  u16*   stb   = (u16*)(ws + OFF_STB);
  u16*   wab   = (u16*)(ws + OFF_WAB);
  u16*   wbb   = (u16*)(ws + OFF_WBB);
  u16*   whhbs = (u16*)(ws + OFF_WHHS);
  u16*   whhbq = (u16*)(ws + OFF_WHHQ);
  u16*   wf1   = (u16*)(ws + OFF_WF1);
  u16*   wf2   = (u16*)(ws + OFF_WF2);
  u16*   wf3   = (u16*)(ws + OFF_WF3);
  u16*   sgb   = (u16*)(ws + OFF_SGB);
  u16*   act1  = (u16*)(ws + OFF_ACT1);
  u16*   act2  = (u16*)(ws + OFF_ACT2);

  prep_kernel<<<dim3(4096), dim3(256), 0, stream>>>(
      emb, s_wih, s_bih, s_bhh, q_wih, q_bih, q_bhh,
      g2w, g3w, g4w, g1w, s_whh, q_whh, f1w, f2w, f3w,
      xps, xpq, wb, wab, wbb, tga, tgb, whhbs, whhbq, wf1, wf2, wf3);
  lstm_kernel<<<dim3(672), dim3(64), 0, stream>>>(
      story, question, xps, xpq, whhbs, whhbq, stb, qst);
  pipj_kernel<<<dim3(160,3), dim3(256), 0, stream>>>(
      stb, wab, wbb, tga, tgb, qst, g1w, g1b, pi, pj, qa);
  relnet_kernel<<<dim3(512,5), dim3(256), 0, stream>>>(
      pi, pj, qa, w2b, w3b, w4b, g2b, g3b, g4b, sgp);
  sgred_kernel<<<dim3(512), dim3(256), 0, stream>>>(sgp, sgb);
  fcm_kernel<4,8,256,0><<<dim3(32), dim3(256), 0, stream>>>(sgb, wf1, f1b, act1);
  fcm_kernel<8,8,512,0><<<dim3(32), dim3(256), 0, stream>>>(act1, wf2, f2b, act2);
  fcm_kernel<16,16,1000,1><<<dim3(32), dim3(256), 0, stream>>>(act2, wf3, f3b, (float*)d_out);
}

// Round 5
// 283.428 us; speedup vs baseline: 1.6355x; 1.0902x over previous
//
#include <hip/hip_runtime.h>

typedef unsigned short u16;
typedef unsigned int   u32;
typedef __attribute__((ext_vector_type(8))) short short8;
typedef __attribute__((ext_vector_type(4))) float f32x4;

// ---------------- ws layout (float element offsets) ----------------
#define OFF_XPS   0            // 10000*128 (gate-permuted xp story)
#define OFF_XPQ   1280000      // 10000*128 (gate-permuted xp question)
#define OFF_QST   2560000      // 512*32
#define OFF_PI    2576384      // 512*20*256
#define OFF_PJ    5197824      // 512*20*256
#define OFF_QA    7819264      // 512*256
#define OFF_TGA   7950336      // 20*256
#define OFF_TGB   7955456      // 20*256
#define OFF_WB    7960576      // u16 x 196608 (g2/g3/g4 bf16)
#define OFF_STB   8058880      // u16 x 327680 (story h bf16)
#define OFF_WAB   8222720      // u16 x 8192
#define OFF_WBB   8226816      // u16 x 8192
#define OFF_WHHS  8230912      // u16 x 4096
#define OFF_WHHQ  8232960      // u16 x 4096
#define OFF_WF1   8235008      // u16 x 65536
#define OFF_WF2   8267776      // u16 x 131072
#define OFF_WF3   8333312      // u16 x 524288 (1024x512, zero-padded)
// aliased into XPS/XPQ region (dead after lstm):
#define OFF_SGP   0            // 5*256*512 fl
#define OFF_SGB   655360       // u16 x 131072 (sum_g bf16 [b][256])
#define OFF_ACT1  720896       // u16 x 131072 ([b][256])
#define OFF_ACT2  786432       // u16 x 262144 ([b][512])

__device__ __forceinline__ u16 f2bf(float f){
  union { float f; u32 u; } v; v.f = f;
  u32 u = v.u;
  u32 r = u + 0x7fffu + ((u >> 16) & 1u);
  return (u16)(r >> 16);
}
__device__ __forceinline__ u32 pack2(float a, float b){
  u32 r;
  asm("v_cvt_pk_bf16_f32 %0, %1, %2" : "=v"(r) : "v"(a), "v"(b));
  return r;
}
__device__ __forceinline__ float sigm(float x){
  return __builtin_amdgcn_rcpf(1.f + __expf(-x));
}

// ---------------- prep_xp: xp[v][g] tables, W staged in LDS ----------------
// one v per thread; g-loop with broadcast LDS reads of the W row.
__global__ __launch_bounds__(256) void prep_xp_kernel(
    const float* __restrict__ emb,
    const float* __restrict__ swih, const float* __restrict__ sbih, const float* __restrict__ sbhh,
    const float* __restrict__ qwih, const float* __restrict__ qbih, const float* __restrict__ qbhh,
    float* __restrict__ xps, float* __restrict__ xpq)
{
  __shared__ float wl[4096];
  __shared__ float bl[128];
  const int tid = threadIdx.x;
  const bool isq = blockIdx.y;
  const float* wih = isq ? qwih : swih;
  const float* bih = isq ? qbih : sbih;
  const float* bhh = isq ? qbhh : sbhh;
  float* xp = isq ? xpq : xps;
  #pragma unroll
  for (int k=0;k<16;k++) wl[k*256+tid] = wih[k*256+tid];
  if (tid < 128) bl[tid] = bih[tid] + bhh[tid];
  __syncthreads();
  const int v = blockIdx.x*256 + tid;
  if (v >= 10000) return;
  float4 e[8];
  #pragma unroll
  for (int q=0;q<8;q++) e[q] = *(const float4*)(emb + v*32 + q*4);
  for (int g=0; g<128; ++g){
    float acc = bl[g];
    #pragma unroll
    for (int q=0;q<8;q++){
      float4 w4 = *(const float4*)(&wl[g*32 + q*4]);
      acc = fmaf(e[q].x, w4.x, acc); acc = fmaf(e[q].y, w4.y, acc);
      acc = fmaf(e[q].z, w4.z, acc); acc = fmaf(e[q].w, w4.w, acc);
    }
    // gate-permuted slot
    xp[v*128 + (g&15)*8 + (g>>4)] = acc;
  }
}

// ---------------- prep_misc: bf16 weight conversion + tag tables ----------------
__global__ __launch_bounds__(256) void prep_kernel(
    const float* __restrict__ g2w, const float* __restrict__ g3w, const float* __restrict__ g4w,
    const float* __restrict__ g1w,
    const float* __restrict__ swhh, const float* __restrict__ qwhh,
    const float* __restrict__ f1w, const float* __restrict__ f2w, const float* __restrict__ f3w,
    u16* __restrict__ wb,
    u16* __restrict__ wab, u16* __restrict__ wbb,
    float* __restrict__ tga, float* __restrict__ tgb,
    u16* __restrict__ whhbs, u16* __restrict__ whhbq,
    u16* __restrict__ wf1, u16* __restrict__ wf2, u16* __restrict__ wf3)
{
  const int B = 196608;
  const int C = B + 16384;
  const int D = C + 10240;
  const int E = D + 8192;
  const int F = E + 65536;
  const int G = F + 131072;
  const int H = G + 524288;
  for (int idx = blockIdx.x*256 + threadIdx.x; idx < H; idx += gridDim.x*256){
    if (idx < B){
      const int k = idx;
      const float* src = (k < 65536) ? g2w : ((k < 131072) ? g3w : g4w);
      wb[k] = f2bf(src[k & 65535]);
    } else if (idx < C){
      const int k = idx - B;
      if (k < 8192) wab[k] = f2bf(g1w[(k>>5)*136 + (k&31)]);
      else { const int k2 = k - 8192; wbb[k2] = f2bf(g1w[(k2>>5)*136 + 52 + (k2&31)]); }
    } else if (idx < D){
      const int k = idx - C;
      if (k < 5120){ const int s = k >> 8, g = k & 255; tga[k] = g1w[g*136 + 32 + s]; }
      else { const int k2 = k - 5120; const int s = k2 >> 8, g = k2 & 255; tgb[k2] = g1w[g*136 + 84 + s]; }
    } else if (idx < E){
      const int k = idx - D;
      if (k < 4096) whhbs[k] = f2bf(swhh[k]);
      else whhbq[k-4096] = f2bf(qwhh[k-4096]);
    } else if (idx < F){
      const int k = idx - E;
      wf1[k] = f2bf(f1w[k]);
    } else if (idx < G){
      const int k = idx - F;
      wf2[k] = f2bf(f2w[k]);
    } else {
      const int k = idx - G;
      const int o = k >> 9, kk = k & 511;
      wf3[k] = (o < 1000) ? f2bf(f3w[o*512 + kk]) : (u16)0;
    }
  }
}

// ---------------- LSTM via MFMA: 16 sequences per wave ----------------
template<int LEN>
__device__ __forceinline__ void lstm_mfma_run(
    const int* __restrict__ toks, int s0,
    const float* __restrict__ xpr, const u16* __restrict__ whhb,
    u16* __restrict__ hl, int lane, float* h0r, float* h1r)
{
  const int l15 = lane & 15, l4 = lane >> 4;
  short8 wf[8];
  #pragma unroll
  for (int f=0; f<8; f++)
    wf[f] = *(const short8*)(whhb + (f*16+l15)*32 + l4*8);
  short8 ha = (short8){0,0,0,0,0,0,0,0};
  float c0[4] = {0,0,0,0}, c1[4] = {0,0,0,0};
  int tk[4];
  #pragma unroll
  for (int r=0;r<4;r++) tk[r] = toks[(s0 + l4*4 + r)*LEN];
  float4 xa[4], xb[4];
  #pragma unroll
  for (int r=0;r<4;r++){
    xa[r] = *(const float4*)(xpr + tk[r]*128 + l15*8);
    xb[r] = *(const float4*)(xpr + tk[r]*128 + l15*8 + 4);
  }
  #pragma unroll
  for (int t=0; t<LEN; ++t){
    int tkn[4];
    if (t+1 < LEN){
      #pragma unroll
      for (int r=0;r<4;r++) tkn[r] = toks[(s0 + l4*4 + r)*LEN + t + 1];
    }
    const f32x4 z = (f32x4){0.f,0.f,0.f,0.f};
    f32x4 acc[8];
    #pragma unroll
    for (int f=0; f<8; f++)
      acc[f] = __builtin_amdgcn_mfma_f32_16x16x32_bf16(ha, wf[f], z, 0, 0, 0);
    float4 na[4], nb[4];
    if (t+1 < LEN){
      #pragma unroll
      for (int r=0;r<4;r++){
        na[r] = *(const float4*)(xpr + tkn[r]*128 + l15*8);
        nb[r] = *(const float4*)(xpr + tkn[r]*128 + l15*8 + 4);
      }
    }
    #pragma unroll
    for (int r=0;r<4;r++){
      float i0 = sigm(acc[0][r] + xa[r].x);
      float f0 = sigm(acc[2][r] + xa[r].z);
      float g0 = 2.f*sigm(2.f*(acc[4][r] + xb[r].x)) - 1.f;
      float o0 = sigm(acc[6][r] + xb[r].z);
      c0[r] = fmaf(f0, c0[r], i0*g0);
      h0r[r] = o0 * (2.f*sigm(2.f*c0[r]) - 1.f);
      float i1 = sigm(acc[1][r] + xa[r].y);
      float f1v = sigm(acc[3][r] + xa[r].w);
      float g1v = 2.f*sigm(2.f*(acc[5][r] + xb[r].y)) - 1.f;
      float o1 = sigm(acc[7][r] + xb[r].w);
      c1[r] = fmaf(f1v, c1[r], i1*g1v);
      h1r[r] = o1 * (2.f*sigm(2.f*c1[r]) - 1.f);
    }
    if (t+1 < LEN){
      #pragma unroll
      for (int r=0;r<4;r++){
        hl[(l4*4+r)*32 + l15]      = f2bf(h0r[r]);
        hl[(l4*4+r)*32 + 16 + l15] = f2bf(h1r[r]);
      }
      __syncthreads();
      ha = *(const short8*)(hl + l15*32 + l4*8);
      #pragma unroll
      for (int r=0;r<4;r++){ xa[r] = na[r]; xb[r] = nb[r]; }
    }
  }
}

__global__ __launch_bounds__(64) void lstm_kernel(
    const int* __restrict__ story, const int* __restrict__ question,
    const float* __restrict__ xprs, const float* __restrict__ xprq,
    const u16* __restrict__ whhbs, const u16* __restrict__ whhbq,
    u16* __restrict__ stb, float* __restrict__ qst)
{
  __shared__ u16 hl[512];
  const int lane = threadIdx.x;
  const int w = blockIdx.x;
  const int l15 = lane & 15, l4 = lane >> 4;
  float h0r[4], h1r[4];
  if (w >= 640){
    const int s0 = (w - 640)*16;
    lstm_mfma_run<16>(question, s0, xprq, whhbq, hl, lane, h0r, h1r);
    #pragma unroll
    for (int r=0;r<4;r++){
      qst[(s0 + l4*4 + r)*32 + l15]      = h0r[r];
      qst[(s0 + l4*4 + r)*32 + 16 + l15] = h1r[r];
    }
  } else {
    const int s0 = w*16;
    lstm_mfma_run<32>(story, s0, xprs, whhbs, hl, lane, h0r, h1r);
    #pragma unroll
    for (int r=0;r<4;r++){
      stb[(s0 + l4*4 + r)*32 + l15]      = f2bf(h0r[r]);
      stb[(s0 + l4*4 + r)*32 + 16 + l15] = f2bf(h1r[r]);
    }
  }
}

// ---------------- pi / pj via MFMA (K=32, one step); y==2 computes qa ----------------
__global__ __launch_bounds__(256) void pipj_kernel(
    const u16* __restrict__ stb, const u16* __restrict__ wab, const u16* __restrict__ wbb,
    const float* __restrict__ tga, const float* __restrict__ tgb,
    const float* __restrict__ qst, const float* __restrict__ g1w, const float* __restrict__ g1b,
    float* __restrict__ pi, float* __restrict__ pj, float* __restrict__ qa)
{
  const int tid = threadIdx.x;
  if (blockIdx.y == 2){
    for (int idx = blockIdx.x*256 + tid; idx < 131072; idx += 160*256){
      const int b = idx >> 8, g = idx & 255;
      const float* qs = qst + b*32;
      const float* wr = g1w + g*136 + 104;
      float acc = g1b[g];
      #pragma unroll
      for (int q=0;q<8;q++){
        float4 s4 = *(const float4*)(qs + q*4);
        float4 w4 = *(const float4*)(wr + q*4);
        acc = fmaf(s4.x, w4.x, acc); acc = fmaf(s4.y, w4.y, acc);
        acc = fmaf(s4.z, w4.z, acc); acc = fmaf(s4.w, w4.w, acc);
      }
      qa[idx] = acc;
    }
    return;
  }
  const int lane = tid & 63;
  const int wv = tid >> 6;
  const int l15 = lane & 15;
  const int l4 = lane >> 4;
  const int bs0 = blockIdx.x * 64;
  const bool isj = blockIdx.y;
  const u16* wB = isj ? wbb : wab;
  const float* tg = isj ? tgb : tga;
  float* out = isj ? pj : pi;

  short8 af[4], bf[4];
  #pragma unroll
  for (int mf=0; mf<4; mf++)
    af[mf] = *(const short8*)(stb + (bs0 + mf*16 + l15)*32 + l4*8);
  #pragma unroll
  for (int nf=0; nf<4; nf++)
    bf[nf] = *(const short8*)(wB + (wv*64 + nf*16 + l15)*32 + l4*8);

  #pragma unroll
  for (int mf=0; mf<4; mf++){
    #pragma unroll
    for (int nf=0; nf<4; nf++){
      f32x4 acc = (f32x4){0.f,0.f,0.f,0.f};
      acc = __builtin_amdgcn_mfma_f32_16x16x32_bf16(af[mf], bf[nf], acc, 0, 0, 0);
      const int g = wv*64 + nf*16 + l15;
      #pragma unroll
      for (int r=0; r<4; r++){
        const int bs = bs0 + mf*16 + l4*4 + r;
        const int s = bs % 20;
        out[bs*256 + g] = acc[r] + tg[s*256 + g];
      }
    }
  }
}

// ---------------- core relational MLP: 1 tile per block, 8 waves ----------------
// grid (512 b, 5 t); X tile bf16 in LDS [80][256] XOR-swizzled
#define SWZ(m, col) ((m)*256 + ((col) ^ (((m)&7)<<3)))
__global__ __launch_bounds__(512) void relnet_kernel(
    const float* __restrict__ pi, const float* __restrict__ pj, const float* __restrict__ qa,
    const u16* __restrict__ w2, const u16* __restrict__ w3, const u16* __restrict__ w4,
    const float* __restrict__ b2, const float* __restrict__ b3, const float* __restrict__ b4,
    float* __restrict__ sgp)
{
  __shared__ u16 Xs[80*256];
  const int tid = threadIdx.x;
  const int lane = tid & 63;
  const int wv  = tid >> 6;       // 0..7 -> h-range wv*32
  const int b   = blockIdx.x;
  const int t   = blockIdx.y;
  const int l15 = lane & 15;
  const int l4  = lane >> 4;

  const float* pib = pi + b*(20*256);
  const float* pjb = pj + b*(20*256);
  const float* qab = qa + b*256;

  float sums[2][4] = {{0.f}};

  // ---- X1 = relu(pi + pj + qa) -> LDS bf16 (swizzled) ----
  #pragma unroll
  for (int it = 0; it < 5; ++it){
    int u  = it*512 + tid;
    int m  = u >> 5;
    int gq = (u & 31) << 3;
    int R  = t*80 + m;
    int i  = R / 20;
    int j  = R - i*20;
    const float4* pr = (const float4*)(pib + i*256 + gq);
    const float4* qr = (const float4*)(pjb + j*256 + gq);
    const float4* ar = (const float4*)(qab + gq);
    uint4 pk;
    {
      float4 a = pr[0], c4 = qr[0], d4 = ar[0];
      pk.x = pack2(fmaxf(a.x+c4.x+d4.x,0.f), fmaxf(a.y+c4.y+d4.y,0.f));
      pk.y = pack2(fmaxf(a.z+c4.z+d4.z,0.f), fmaxf(a.w+c4.w+d4.w,0.f));
    }
    {
      float4 a = pr[1], c4 = qr[1], d4 = ar[1];
      pk.z = pack2(fmaxf(a.x+c4.x+d4.x,0.f), fmaxf(a.y+c4.y+d4.y,0.f));
      pk.w = pack2(fmaxf(a.z+c4.z+d4.z,0.f), fmaxf(a.w+c4.w+d4.w,0.f));
    }
    *(uint4*)(&Xs[SWZ(m, gq)]) = pk;
  }
  __syncthreads();

  for (int lay = 0; lay < 3; ++lay){
    const u16*   W    = (lay==0) ? w2 : ((lay==1) ? w3 : w4);
    const float* bias = (lay==0) ? b2 : ((lay==1) ? b3 : b4);
    f32x4 acc[2][5];
    #pragma unroll
    for (int hf=0; hf<2; hf++)
      #pragma unroll
      for (int mf=0; mf<5; mf++)
        acc[hf][mf] = (f32x4){0.f,0.f,0.f,0.f};

    #pragma unroll
    for (int kk = 0; kk < 8; ++kk){
      short8 af[2], xf[5];
      #pragma unroll
      for (int hf=0; hf<2; hf++){
        int row = wv*32 + hf*16 + l15;
        af[hf] = *(const short8*)(W + row*256 + kk*32 + l4*8);
      }
      #pragma unroll
      for (int mf=0; mf<5; mf++){
        xf[mf] = *(const short8*)(&Xs[SWZ(mf*16 + l15, kk*32 + l4*8)]);
      }
      #pragma unroll
      for (int hf=0; hf<2; hf++)
        #pragma unroll
        for (int mf=0; mf<5; mf++)
          acc[hf][mf] = __builtin_amdgcn_mfma_f32_16x16x32_bf16(af[hf], xf[mf], acc[hf][mf], 0, 0, 0);
    }

    if (lay < 2){
      __syncthreads();   // all reads of Xs complete
      #pragma unroll
      for (int hf=0; hf<2; hf++){
        int h0 = wv*32 + hf*16 + l4*4;
        float4 bi = *(const float4*)(bias + h0);
        #pragma unroll
        for (int mf=0; mf<5; mf++){
          int m = mf*16 + l15;
          uint2 pk;
          pk.x = pack2(fmaxf(acc[hf][mf][0]+bi.x,0.f), fmaxf(acc[hf][mf][1]+bi.y,0.f));
          pk.y = pack2(fmaxf(acc[hf][mf][2]+bi.z,0.f), fmaxf(acc[hf][mf][3]+bi.w,0.f));
          *(uint2*)(&Xs[SWZ(m, h0)]) = pk;
        }
      }
      __syncthreads();
    } else {
      #pragma unroll
      for (int hf=0; hf<2; hf++){
        int h0 = wv*32 + hf*16 + l4*4;
        float4 bi = *(const float4*)(bias + h0);
        #pragma unroll
        for (int mf=0; mf<5; mf++){
          sums[hf][0] += fmaxf(acc[hf][mf][0]+bi.x,0.f);
          sums[hf][1] += fmaxf(acc[hf][mf][1]+bi.y,0.f);
          sums[hf][2] += fmaxf(acc[hf][mf][2]+bi.z,0.f);
          sums[hf][3] += fmaxf(acc[hf][mf][3]+bi.w,0.f);
        }
      }
    }
  }

  // reduce over the 16 m-lanes, write partial sum sgp[t][h][b]
  #pragma unroll
  for (int hf=0; hf<2; hf++){
    #pragma unroll
    for (int r=0; r<4; r++){
      float v = sums[hf][r];
      v += __shfl_xor(v, 1);
      v += __shfl_xor(v, 2);
      v += __shfl_xor(v, 4);
      v += __shfl_xor(v, 8);
      if (l15 == 0){
        int h = wv*32 + hf*16 + l4*4 + r;
        sgp[t*131072 + h*512 + b] = v;
      }
    }
  }
}

// ---------------- partial-sum reduce -> bf16 [b][256] ----------------
__global__ __launch_bounds__(256) void sgred_kernel(
    const float* __restrict__ sgp, u16* __restrict__ sgb)
{
  const int idx = blockIdx.x*256 + threadIdx.x;  // g*512 + b
  float v = 0.f;
  #pragma unroll
  for (int t=0;t<5;t++) v += sgp[t*131072 + idx];
  const int g = idx >> 9, b = idx & 511;
  sgb[b*256 + g] = f2bf(v);
}

// ---------------- fc layers via MFMA ----------------
template<int HF, int KK, int OREAL, int MODE>
__global__ __launch_bounds__(256) void fcm_kernel(
    const u16* __restrict__ in, const u16* __restrict__ w,
    const float* __restrict__ bias, void* __restrict__ outp)
{
  const int K = KK*32;
  const int O = HF*64;
  const int tid = threadIdx.x, lane = tid & 63, wv = tid >> 6;
  const int l15 = lane & 15, l4 = lane >> 4;
  const int b0 = blockIdx.x*16;
  f32x4 acc[HF];
  #pragma unroll
  for (int hf=0; hf<HF; hf++) acc[hf] = (f32x4){0.f,0.f,0.f,0.f};
  #pragma unroll 4
  for (int kk=0; kk<KK; ++kk){
    short8 xf = *(const short8*)(in + (b0+l15)*K + kk*32 + l4*8);
    #pragma unroll
    for (int hf=0; hf<HF; hf++){
      short8 af = *(const short8*)(w + (wv*HF*16 + hf*16 + l15)*K + kk*32 + l4*8);
      acc[hf] = __builtin_amdgcn_mfma_f32_16x16x32_bf16(af, xf, acc[hf], 0, 0, 0);
    }
  }
  const int b = b0 + l15;
  #pragma unroll
  for (int hf=0; hf<HF; hf++){
    const int o0 = wv*HF*16 + hf*16 + l4*4;
    float v[4];
    #pragma unroll
    for (int r=0;r<4;r++){
      float bv = (o0+r < OREAL) ? bias[o0+r] : 0.f;
      v[r] = acc[hf][r] + bv;
    }
    if (MODE == 0){
      uint2 pk;
      pk.x = pack2(fmaxf(v[0],0.f), fmaxf(v[1],0.f));
      pk.y = pack2(fmaxf(v[2],0.f), fmaxf(v[3],0.f));
      *(uint2*)((u16*)outp + (size_t)b*O + o0) = pk;
    } else {
      float* of = (float*)outp;
      #pragma unroll
      for (int r=0;r<4;r++)
        if (o0+r < OREAL) of[(size_t)b*OREAL + o0 + r] = v[r];
    }
  }
}

// ---------------- launch ----------------
extern "C" void kernel_launch(void* const* d_in, const int* in_sizes, int n_in,
                              void* d_out, int out_size, void* d_ws, size_t ws_size,
                              hipStream_t stream)
{
  const int*   story    = (const int*)d_in[0];
  const int*   question = (const int*)d_in[1];
  const float* emb   = (const float*)d_in[2];
  const float* s_wih = (const float*)d_in[3];
  const float* s_whh = (const float*)d_in[4];
  const float* s_bih = (const float*)d_in[5];
  const float* s_bhh = (const float*)d_in[6];
  const float* q_wih = (const float*)d_in[7];
  const float* q_whh = (const float*)d_in[8];
  const float* q_bih = (const float*)d_in[9];
  const float* q_bhh = (const float*)d_in[10];
  const float* g1w = (const float*)d_in[11];
  const float* g1b = (const float*)d_in[12];
  const float* g2w = (const float*)d_in[13];
  const float* g2b = (const float*)d_in[14];
  const float* g3w = (const float*)d_in[15];
  const float* g3b = (const float*)d_in[16];
  const float* g4w = (const float*)d_in[17];
  const float* g4b = (const float*)d_in[18];
  const float* f1w = (const float*)d_in[19];
  const float* f1b = (const float*)d_in[20];
  const float* f2w = (const float*)d_in[21];
  const float* f2b = (const float*)d_in[22];
  const float* f3w = (const float*)d_in[23];
  const float* f3b = (const float*)d_in[24];

  float* ws  = (float*)d_ws;
  float* xps = ws + OFF_XPS;
  float* xpq = ws + OFF_XPQ;
  float* qst = ws + OFF_QST;
  float* pi  = ws + OFF_PI;
  float* pj  = ws + OFF_PJ;
  float* qa  = ws + OFF_QA;
  float* tga = ws + OFF_TGA;
  float* tgb = ws + OFF_TGB;
  float* sgp = ws + OFF_SGP;
  u16*   wb    = (u16*)(ws + OFF_WB);
  u16*   w2b   = wb;
  u16*   w3b   = wb + 65536;
  u16*   w4b   = wb + 131072;
  u16*   stb   = (u16*)(ws + OFF_STB);
  u16*   wab   = (u16*)(ws + OFF_WAB);
  u16*   wbb   = (u16*)(ws + OFF_WBB);
  u16*   whhbs = (u16*)(ws + OFF_WHHS);
  u16*   whhbq = (u16*)(ws + OFF_WHHQ);
  u16*   wf1   = (u16*)(ws + OFF_WF1);
  u16*   wf2   = (u16*)(ws + OFF_WF2);
  u16*   wf3   = (u16*)(ws + OFF_WF3);
  u16*   sgb   = (u16*)(ws + OFF_SGB);
  u16*   act1  = (u16*)(ws + OFF_ACT1);
  u16*   act2  = (u16*)(ws + OFF_ACT2);

  prep_xp_kernel<<<dim3(40,2), dim3(256), 0, stream>>>(
      emb, s_wih, s_bih, s_bhh, q_wih, q_bih, q_bhh, xps, xpq);
  prep_kernel<<<dim3(1024), dim3(256), 0, stream>>>(
      g2w, g3w, g4w, g1w, s_whh, q_whh, f1w, f2w, f3w,
      wb, wab, wbb, tga, tgb, whhbs, whhbq, wf1, wf2, wf3);
  lstm_kernel<<<dim3(672), dim3(64), 0, stream>>>(
      story, question, xps, xpq, whhbs, whhbq, stb, qst);
  pipj_kernel<<<dim3(160,3), dim3(256), 0, stream>>>(
      stb, wab, wbb, tga, tgb, qst, g1w, g1b, pi, pj, qa);
  relnet_kernel<<<dim3(512,5), dim3(512), 0, stream>>>(
      pi, pj, qa, w2b, w3b, w4b, g2b, g3b, g4b, sgp);
  sgred_kernel<<<dim3(512), dim3(256), 0, stream>>>(sgp, sgb);
  fcm_kernel<4,8,256,0><<<dim3(32), dim3(256), 0, stream>>>(sgb, wf1, f1b, act1);
  fcm_kernel<8,8,512,0><<<dim3(32), dim3(256), 0, stream>>>(act1, wf2, f2b, act2);
  fcm_kernel<16,16,1000,1><<<dim3(32), dim3(256), 0, stream>>>(act2, wf3, f3b, (float*)d_out);
}